// Round 5
// baseline (1419.357 us; speedup 1.0000x reference)
//
#include <hip/hip_runtime.h>
#include <math.h>

#define NLAYERS   4
#define D_MODEL   256
#define D_INNER   512
#define D_STATE   16
#define NHEADS    8
#define HEADDIM   64
#define D_CONV    4
#define D_INT     256
#define NCLS      10
#define IN_FEAT   64
#define T_LEN     1024
#define BATCH     8
#define D_IN_PROJ 1064   // 2*512 + 2*16 + 8
#define CONV_DIM  544    // 512 + 32
#define EPS       1e-5f
#define NTOK      (BATCH*T_LEN)   // 8192
#define QCH       64             // scan chunk length
#define NCH       (T_LEN/QCH)    // 16 chunks

typedef __attribute__((ext_vector_type(8))) short bf16x8;
typedef __attribute__((ext_vector_type(4))) float f32x4;

__device__ __forceinline__ float silu_f(float x) { return x / (1.f + expf(-x)); }
__device__ __forceinline__ float softplus_f(float x) { return x > 20.f ? x : log1pf(expf(x)); }

// ---- async global->LDS 16B DMA (dest must be wave-uniform base + lane*16) ----
typedef __attribute__((address_space(3))) void       lds_void_t;
typedef __attribute__((address_space(1))) const void gbl_void_t;
__device__ __forceinline__ void gload16(void* lds, const void* g) {
    __builtin_amdgcn_global_load_lds((gbl_void_t*)g, (lds_void_t*)lds, 16, 0, 0);
}

// ---- fp32 -> bf16 (RNE) split helpers ----
__device__ __forceinline__ unsigned short f2bf(float f) {
    unsigned u = __float_as_uint(f);
    return (unsigned short)((u + 0x7fffu + ((u >> 16) & 1u)) >> 16);
}
__device__ __forceinline__ float bf2f(unsigned short h) {
    return __uint_as_float((unsigned)h << 16);
}
__device__ __forceinline__ ushort2 split2(float f) {
    unsigned short hi = f2bf(f);
    unsigned short lo = f2bf(f - bf2f(hi));
    return make_ushort2(hi, lo);
}

// ---- block reduction: NW waves of 64 lanes ----
template<int NW>
__device__ __forceinline__ float block_sum(float v, float* red) {
#pragma unroll
    for (int off = 32; off > 0; off >>= 1) v += __shfl_down(v, off, 64);
    int lane = threadIdx.x & 63, wid = threadIdx.x >> 6;
    __syncthreads();
    if (lane == 0) red[wid] = v;
    __syncthreads();
    float s = 0.f;
#pragma unroll
    for (int i = 0; i < NW; ++i) s += red[i];
    return s;
}

// ---- weight pack: fp32 -> (hi,lo) bf16, vectorized ----
__global__ __launch_bounds__(256) void pack_split_kernel(
    const float* __restrict__ src, unsigned short* __restrict__ hi,
    unsigned short* __restrict__ lo, int n4)
{
    int i = blockIdx.x * 256 + threadIdx.x;
    if (i >= n4) return;
    float4 v = ((const float4*)src)[i];
    ushort2 a = split2(v.x), b = split2(v.y), c = split2(v.z), d = split2(v.w);
    ((ushort4*)hi)[i] = make_ushort4(a.x, b.x, c.x, d.x);
    ((ushort4*)lo)[i] = make_ushort4(a.y, b.y, c.y, d.y);
}

// ---- input projection: h[b,t,d] = sum_f x[b,f,t]*W[d,f] + bias[d] ----
__global__ __launch_bounds__(256) void input_proj_kernel(
    const float* __restrict__ x, const float* __restrict__ w,
    const float* __restrict__ bias, float* __restrict__ h)
{
    int bt = blockIdx.x;
    int b = bt / T_LEN, t = bt % T_LEN;
    __shared__ float xs[IN_FEAT];
    int tid = threadIdx.x;
    if (tid < IN_FEAT) xs[tid] = x[(b * IN_FEAT + tid) * T_LEN + t];
    __syncthreads();
    float acc = bias[tid];
    const float4* wr = (const float4*)(w + tid * IN_FEAT);
#pragma unroll 4
    for (int f4 = 0; f4 < IN_FEAT / 4; ++f4) {
        float4 wv = wr[f4];
        acc += xs[f4 * 4 + 0] * wv.x + xs[f4 * 4 + 1] * wv.y +
               xs[f4 * 4 + 2] * wv.z + xs[f4 * 4 + 3] * wv.w;
    }
    h[bt * D_MODEL + tid] = acc;
}

// ---- fused (optional add) + LayerNorm over 256, writes packed hi/lo and/or f32 ----
__global__ __launch_bounds__(256) void add_ln_kernel(
    const float* __restrict__ a, const float* __restrict__ b,
    float* __restrict__ sum_out, unsigned short* __restrict__ hi,
    unsigned short* __restrict__ lo, float* __restrict__ f32out,
    const float* __restrict__ w, const float* __restrict__ bias)
{
    __shared__ float red[4];
    int row = blockIdx.x, d = threadIdx.x;
    size_t o = (size_t)row * D_MODEL + d;
    float v = a[o];
    if (b) v += b[o];
    if (sum_out) sum_out[o] = v;
    float mean = block_sum<4>(v, red) * (1.f / D_MODEL);
    float xc = v - mean;
    float var = block_sum<4>(xc * xc, red) * (1.f / D_MODEL);
    float r = xc * rsqrtf(var + EPS) * w[d] + bias[d];
    if (hi) { ushort2 s = split2(r); hi[o] = s.x; lo[o] = s.y; }
    if (f32out) f32out[o] = r;
}

// ---- MFMA GEMM: C[m][n] = sum_k A[m][k]*W[n][k] (+bias[n]) (+resid)
// fp32-accurate via 3-pass bf16 split (hh + hl + lh).
// Tile BM x 64, BK=32; 128 threads = 2 waves; wave tile (BM/2) x 64.
// BM=128 for large-N GEMMs (reuse); BM=64 for small-N GEMMs (grid coverage:
// N=256 => 512 blocks = 2/CU instead of 256 = 1/CU, so resident waves cover
// each other's vmcnt-drain stall).
// Staging via global_load_lds width=16 (LDS dest linear in tid => wave-uniform+lane*16).
template<int BM>
__global__ __launch_bounds__(128) void gemm_mfma(
    const unsigned short* __restrict__ Ahi, const unsigned short* __restrict__ Alo,
    const unsigned short* __restrict__ Whi, const unsigned short* __restrict__ Wlo,
    const float* __restrict__ bias, const float* __restrict__ resid,
    float* __restrict__ C, int N, int K)
{
    constexpr int MFRAG   = BM / 32;   // m-fragments per wave (16 rows each)
    constexpr int AROUNDS = BM / 32;   // staging rounds of 32 rows
    __shared__ unsigned short sAh[BM * 32], sAl[BM * 32];
    __shared__ unsigned short sBh[64 * 32], sBl[64 * 32];
    const int tid = threadIdx.x;          // 0..127
    const int lane = tid & 63, wm = tid >> 6;
    const int m0 = blockIdx.y * BM, n0 = blockIdx.x * 64;

    // staging: thread covers 8 ushorts at row=tid/4 (+32 per round), k=(tid%4)*8
    const int srow = tid >> 2;            // 0..31
    const int sk   = (tid & 3) * 8;
    const unsigned short* gAh = Ahi + (size_t)(m0 + srow) * K + sk;
    const unsigned short* gAl = Alo + (size_t)(m0 + srow) * K + sk;
    int bn  = n0 + srow;      if (bn  > N - 1) bn  = N - 1;  // clamp tail (masked at store)
    int bn2 = n0 + 32 + srow; if (bn2 > N - 1) bn2 = N - 1;
    const unsigned short* gBh  = Whi + (size_t)bn  * K + sk;
    const unsigned short* gBh2 = Whi + (size_t)bn2 * K + sk;
    const unsigned short* gBl  = Wlo + (size_t)bn  * K + sk;
    const unsigned short* gBl2 = Wlo + (size_t)bn2 * K + sk;
    const size_t rK32 = (size_t)32 * K;   // +32 rows

    const int fr = lane & 15, kg = lane >> 4;
    const int abase = (wm * (BM / 2) + fr) * 32 + kg * 8;
    const int bbase = fr * 32 + kg * 8;

    f32x4 acc[MFRAG][4] = {};

    for (int k0 = 0; k0 < K; k0 += 32) {
        // issue direct-to-LDS DMAs (LDS free: post-barrier of prev iter)
#pragma unroll
        for (int rr = 0; rr < AROUNDS; ++rr) {
            gload16(&sAh[tid * 8 + rr * 1024], gAh + (size_t)rr * rK32);
            gload16(&sAl[tid * 8 + rr * 1024], gAl + (size_t)rr * rK32);
        }
        gload16(&sBh[tid * 8],        gBh);
        gload16(&sBh[tid * 8 + 1024], gBh2);
        gload16(&sBl[tid * 8],        gBl);
        gload16(&sBl[tid * 8 + 1024], gBl2);
        gAh += 32; gAl += 32; gBh += 32; gBh2 += 32; gBl += 32; gBl2 += 32;
        __syncthreads();   // compiler emits vmcnt(0) drain: DMA landed

        bf16x8 ah[MFRAG], al[MFRAG], bh[4], bl[4];
#pragma unroll
        for (int fm = 0; fm < MFRAG; ++fm) {
            ah[fm] = *(const bf16x8*)&sAh[abase + fm * 512];
            al[fm] = *(const bf16x8*)&sAl[abase + fm * 512];
        }
#pragma unroll
        for (int fn = 0; fn < 4; ++fn) {
            bh[fn] = *(const bf16x8*)&sBh[bbase + fn * 512];
            bl[fn] = *(const bf16x8*)&sBl[bbase + fn * 512];
        }
#pragma unroll
        for (int fm = 0; fm < MFRAG; ++fm)
#pragma unroll
            for (int fn = 0; fn < 4; ++fn) {
                acc[fm][fn] = __builtin_amdgcn_mfma_f32_16x16x32_bf16(ah[fm], bh[fn], acc[fm][fn], 0, 0, 0);
                acc[fm][fn] = __builtin_amdgcn_mfma_f32_16x16x32_bf16(ah[fm], bl[fn], acc[fm][fn], 0, 0, 0);
                acc[fm][fn] = __builtin_amdgcn_mfma_f32_16x16x32_bf16(al[fm], bh[fn], acc[fm][fn], 0, 0, 0);
            }
        __syncthreads();   // all LDS reads done before next iter's DMA
    }

    // epilogue: C/D layout col=lane&15, row=(lane>>4)*4+reg  [m89-verified]
    const int orow0 = kg * 4;
#pragma unroll
    for (int fm = 0; fm < MFRAG; ++fm)
#pragma unroll
        for (int fn = 0; fn < 4; ++fn) {
            int n = n0 + fn * 16 + fr;
            if (n < N) {
                float bv = bias ? bias[n] : 0.f;
#pragma unroll
                for (int r = 0; r < 4; ++r) {
                    int m = m0 + wm * (BM / 2) + fm * 16 + orow0 + r;
                    size_t off = (size_t)m * N + n;
                    float v = acc[fm][fn][r] + bv;
                    if (resid) v += resid[off];
                    C[off] = v;
                }
            }
        }
}

// ---- depthwise causal conv (K=4) + silu (float4 over channels), fused dt/dA ----
// thread owns 4 consecutive channels of one output token; all loads/stores 16B.
__global__ __launch_bounds__(256) void conv_dt_kernel(
    const float* __restrict__ zx, const float* __restrict__ cw,
    const float* __restrict__ cb, const float* __restrict__ dt_bias,
    const float* __restrict__ A_log, float* __restrict__ out,
    float2* __restrict__ dtda, int dir)
{
    const int NCG = CONV_DIM / 4;   // 136
    int idx = blockIdx.x * 256 + threadIdx.x;
    if (idx < NTOK * NCG) {
        int cg = idx % NCG;
        int bt = idx / NCG;
        int c = cg * 4;
        int s = bt % T_LEN, b = bt / T_LEN;
        float4 acc = *(const float4*)(cb + c);
        float4 w0 = *(const float4*)(cw + (c + 0) * 4);   // taps of ch c
        float4 w1 = *(const float4*)(cw + (c + 1) * 4);
        float4 w2 = *(const float4*)(cw + (c + 2) * 4);
        float4 w3 = *(const float4*)(cw + (c + 3) * 4);
#pragma unroll
        for (int k = 0; k < D_CONV; ++k) {
            int sj = s + k - (D_CONV - 1);
            if (sj >= 0) {
                int t = dir ? (T_LEN - 1 - sj) : sj;
                float4 xv = *(const float4*)(zx + ((size_t)(b * T_LEN + t)) * D_IN_PROJ + D_INNER + c);
                acc.x += xv.x * (&w0.x)[k];
                acc.y += xv.y * (&w1.x)[k];
                acc.z += xv.z * (&w2.x)[k];
                acc.w += xv.w * (&w3.x)[k];
            }
        }
        int tout = dir ? (T_LEN - 1 - s) : s;
        float4 r = make_float4(silu_f(acc.x), silu_f(acc.y), silu_f(acc.z), silu_f(acc.w));
        *(float4*)(out + ((size_t)(b * T_LEN + tout)) * CONV_DIM + c) = r;
    } else {
        int j = idx - NTOK * NCG;
        if (j < NTOK * NHEADS) {
            int bt = j >> 3, h = j & 7;
            float dtraw = zx[(size_t)bt * D_IN_PROJ + (D_IN_PROJ - NHEADS) + h] + dt_bias[h];
            float dt = softplus_f(dtraw);
            float Ac = -expf(A_log[h]);
            dtda[(size_t)bt * NHEADS + h] = make_float2(dt, expf(dt * Ac));
        }
    }
}

// ==== chunked SSM scan (dA scalar per head => linear chunk combine) ====
// S1: per-(b,h,chunk) local scan from zero state; writes y_local(+D*x),
//     per-step scalar decay prefix pf, and chunk end-state hend.
__global__ __launch_bounds__(1024) void scan_local_kernel(
    const float2* __restrict__ dtda, const float* __restrict__ xbc,
    const float* __restrict__ Dvec, float* __restrict__ y,
    float* __restrict__ hend, float* __restrict__ pf, int dir)
{
    int bx = blockIdx.x;                  // 1024 = B*H*NCH
    int c = bx & (NCH - 1), h = (bx >> 4) & 7, b = bx >> 7;
    int tid = threadIdx.x, p = tid >> 4, n = tid & 15;
    float Dh = Dvec[h];
    float hreg = 0.f, pp = 1.f;
    int s0 = c * QCH;
    for (int si = 0; si < QCH; ++si) {
        int s = s0 + si;
        int t = dir ? (T_LEN - 1 - s) : s;
        size_t row = (size_t)b * T_LEN + t;
        float2 dd = dtda[row * NHEADS + h];
        float xv = xbc[row * CONV_DIM + h * HEADDIM + p];
        float Bv = xbc[row * CONV_DIM + D_INNER + n];
        float Cv = xbc[row * CONV_DIM + D_INNER + D_STATE + n];
        hreg = hreg * dd.y + (dd.x * xv) * Bv;
        pp *= dd.y;
        float yv = hreg * Cv;
        yv += __shfl_xor(yv, 1, 16);
        yv += __shfl_xor(yv, 2, 16);
        yv += __shfl_xor(yv, 4, 16);
        yv += __shfl_xor(yv, 8, 16);
        if (n == 0) y[row * D_INNER + h * HEADDIM + p] = yv + Dh * xv;
        if (tid == 0) pf[((size_t)(b * NHEADS + h)) * T_LEN + s] = pp;
    }
    hend[((size_t)((b * NHEADS + h) * NCH + c)) * 1024 + tid] = hreg;
}

// S2: per-(b,h), tiny sequential combine over chunks: h_in[c+1] = hend[c] + P_c*h_in[c]
__global__ __launch_bounds__(1024) void scan_combine_kernel(
    const float* __restrict__ hend, const float* __restrict__ pf,
    float* __restrict__ hin_out)
{
    int b = blockIdx.x >> 3, h = blockIdx.x & 7;
    int tid = threadIdx.x;
    size_t base = (size_t)(b * NHEADS + h);
    float hin = 0.f;
    for (int c = 0; c < NCH; ++c) {
        hin_out[(base * NCH + c) * 1024 + tid] = hin;
        float Pc = pf[base * T_LEN + c * QCH + (QCH - 1)];
        hin = hend[(base * NCH + c) * 1024 + tid] + Pc * hin;
    }
}

// S3: per-(b,h,chunk>=1) correction: y[t,p] += pf_t * sum_n h_in[p,n]*C_t[n]
__global__ __launch_bounds__(1024) void scan_fix_kernel(
    const float* __restrict__ hin_in, const float* __restrict__ pf,
    const float* __restrict__ xbc, float* __restrict__ y, int dir)
{
    int c = 1 + (blockIdx.x % (NCH - 1));
    int bh = blockIdx.x / (NCH - 1);
    int b = bh >> 3, h = bh & 7;
    int tid = threadIdx.x, p = tid >> 4, n = tid & 15;
    size_t base = (size_t)(b * NHEADS + h);
    float hin = hin_in[(base * NCH + c) * 1024 + tid];
    int s0 = c * QCH;
    for (int si = 0; si < QCH; ++si) {
        int s = s0 + si;
        int t = dir ? (T_LEN - 1 - s) : s;
        size_t row = (size_t)b * T_LEN + t;
        float Cv = xbc[row * CONV_DIM + D_INNER + D_STATE + n];
        float pfv = pf[base * T_LEN + s];
        float yv = hin * Cv;
        yv += __shfl_xor(yv, 1, 16);
        yv += __shfl_xor(yv, 2, 16);
        yv += __shfl_xor(yv, 4, 16);
        yv += __shfl_xor(yv, 8, 16);
        if (n == 0) y[row * D_INNER + h * HEADDIM + p] += pfv * yv;
    }
}

// ---- gated RMSNorm over 512, writes packed hi/lo ----
__global__ __launch_bounds__(512) void gated_rms_kernel(
    const float* __restrict__ y, const float* __restrict__ zx,
    const float* __restrict__ w, unsigned short* __restrict__ hi,
    unsigned short* __restrict__ lo)
{
    __shared__ float red[8];
    int row = blockIdx.x, d = threadIdx.x;
    float z = zx[(size_t)row * D_IN_PROJ + d];
    float v = y[(size_t)row * D_INNER + d] * silu_f(z);
    float ss = block_sum<8>(v * v, red);
    float r = rsqrtf(ss * (1.f / D_INNER) + EPS);
    float o = v * r * w[d];
    ushort2 s = split2(o);
    size_t off = (size_t)row * D_INNER + d;
    hi[off] = s.x; lo[off] = s.y;
}

// ---- GLU: g = y1 * silu(gate), writes packed hi/lo ----
__global__ __launch_bounds__(256) void glu_kernel(
    const float* __restrict__ yy, unsigned short* __restrict__ hi,
    unsigned short* __restrict__ lo)
{
    int idx = blockIdx.x * 256 + threadIdx.x;
    int m = idx >> 8, j = idx & 255;
    float v = yy[(size_t)m * (2 * D_INT) + j] * silu_f(yy[(size_t)m * (2 * D_INT) + D_INT + j]);
    ushort2 s = split2(v);
    hi[idx] = s.x; lo[idx] = s.y;
}

// ---- final mean over T + logits ----
__global__ void zero_mean_kernel(float* mean) {
    int i = blockIdx.x * 256 + threadIdx.x;
    if (i < BATCH * D_MODEL) mean[i] = 0.f;
}
__global__ __launch_bounds__(256) void mean_kernel(
    const float* __restrict__ hn, float* __restrict__ mean)
{
    int b = blockIdx.x >> 4;
    int slab = blockIdx.x & 15;
    int d = threadIdx.x;
    float s = 0.f;
    int t0 = slab * 64;
    for (int t = t0; t < t0 + 64; ++t) s += hn[((size_t)(b * T_LEN + t)) * D_MODEL + d];
    atomicAdd(&mean[b * D_MODEL + d], s * (1.f / T_LEN));
}
__global__ void logits_kernel(const float* __restrict__ mean,
                              const float* __restrict__ fcw,
                              const float* __restrict__ fcb,
                              float* __restrict__ out)
{
    int tid = threadIdx.x;
    if (tid < BATCH * NCLS) {
        int b = tid / NCLS, c = tid % NCLS;
        float s = fcb[c];
        for (int d = 0; d < D_MODEL; ++d) s += mean[b * D_MODEL + d] * fcw[c * D_MODEL + d];
        out[tid] = s;
    }
}

extern "C" void kernel_launch(void* const* d_in, const int* in_sizes, int n_in,
                              void* d_out, int out_size, void* d_ws, size_t ws_size,
                              hipStream_t stream)
{
    const float* x            = (const float*)d_in[0];
    const float* input_proj_w = (const float*)d_in[1];
    const float* input_proj_b = (const float*)d_in[2];
    const float* norm1_w      = (const float*)d_in[3];
    const float* norm1_b      = (const float*)d_in[4];
    const float* in_proj_w    = (const float*)d_in[5];
    const float* conv_w       = (const float*)d_in[6];
    const float* conv_b       = (const float*)d_in[7];
    const float* dt_bias      = (const float*)d_in[8];
    const float* A_log        = (const float*)d_in[9];
    const float* Dvec         = (const float*)d_in[10];
    const float* ssm_norm_w   = (const float*)d_in[11];
    const float* out_proj_w   = (const float*)d_in[12];
    const float* norm2_w      = (const float*)d_in[13];
    const float* norm2_b      = (const float*)d_in[14];
    const float* fc1_w        = (const float*)d_in[15];
    const float* fc1_b        = (const float*)d_in[16];
    const float* fc2_w        = (const float*)d_in[17];
    const float* fc2_b        = (const float*)d_in[18];
    const float* normf_w      = (const float*)d_in[19];
    const float* normf_b      = (const float*)d_in[20];
    const float* fc_w         = (const float*)d_in[21];
    const float* fc_b         = (const float*)d_in[22];
    float* out = (float*)d_out;

    char* ws = (char*)d_ws;
    float*          RES  = (float*)(ws + 0);                 // 8 MB fp32 8192x256
    float*          H    = (float*)(ws + 8388608);           // 8 MB
    unsigned short* HNh  = (unsigned short*)(ws + 16777216); // 4 MB bf16 8192x256
    unsigned short* HNl  = (unsigned short*)(ws + 20971520); // 4 MB
    float*          ZX   = (float*)(ws + 25165824);          // 33.25 MB fp32 8192x1064
    float*          XBCC = (float*)(ws + 60030976);          // 17 MB fp32 8192x544
    float*          YSSM = (float*)(ws + 77856768);          // 16 MB fp32 8192x512
    unsigned short* YSh  = (unsigned short*)(ws + 94633984); // 8 MB bf16 8192x512
    unsigned short* YSl  = (unsigned short*)(ws + 103022592);// 8 MB
    unsigned short* GLh  = (unsigned short*)(ws + 111411200);// 4 MB bf16 8192x256
    unsigned short* GLl  = (unsigned short*)(ws + 115605504);// 4 MB
    unsigned short* WIH  = (unsigned short*)(ws + 119799808);// 2.08 MB 4x1064x256
    unsigned short* WIL  = (unsigned short*)(ws + 121978880);
    unsigned short* WOH  = (unsigned short*)(ws + 124157952);// 1 MB 4x256x512
    unsigned short* WOL  = (unsigned short*)(ws + 125206528);
    unsigned short* W1H  = (unsigned short*)(ws + 126255104);// 1 MB 4x512x256
    unsigned short* W1L  = (unsigned short*)(ws + 127303680);
    unsigned short* W2H  = (unsigned short*)(ws + 128352256);// 0.5 MB 4x256x256
    unsigned short* W2L  = (unsigned short*)(ws + 128876544);
    float2*         DTDA = (float2*)(ws + 129400832);        // 0.5 MB 8192x8 float2
    float*          MEAN = (float*)(ws + 129925120);         // 8 KB
    float*          YY   = ZX;                 // alias: fc1 f32 out in dead ZX
    float*          HNF  = XBCC;               // alias: final LN f32 out in dead XBCC
    // scan scratch aliased into regions dead during the scan phase:
    float*          PF   = (float*)(ws + 16777216);  // 256 KB in HNh (HN dead conv..norm2)
    float*          HEND = (float*)(ws + 111411200); // 4 MB in GLh (GL dead during scan)
    float*          HIN  = (float*)(ws + 115605504); // 4 MB in GLl

    // pack all layers' weights to bf16 hi/lo (once per call)
    pack_split_kernel<<<1064, 256, 0, stream>>>(in_proj_w,  WIH, WIL, NLAYERS * D_IN_PROJ * D_MODEL / 4);
    pack_split_kernel<<<512,  256, 0, stream>>>(out_proj_w, WOH, WOL, NLAYERS * D_MODEL * D_INNER / 4);
    pack_split_kernel<<<512,  256, 0, stream>>>(fc1_w,      W1H, W1L, NLAYERS * 2 * D_INT * D_MODEL / 4);
    pack_split_kernel<<<256,  256, 0, stream>>>(fc2_w,      W2H, W2L, NLAYERS * D_MODEL * D_INT / 4);

    input_proj_kernel<<<NTOK, 256, 0, stream>>>(x, input_proj_w, input_proj_b, H);

    for (int i = 0; i < NLAYERS; ++i) {
        int dir = i & 1;   // odd layers: reversed-time conv+scan (flip trick)
        // residual = H (+ RES); HN = LN1(residual), packed
        add_ln_kernel<<<NTOK, 256, 0, stream>>>(
            H, i ? RES : nullptr, RES, HNh, HNl, nullptr,
            norm1_w + i * D_MODEL, norm1_b + i * D_MODEL);
        // in_proj: ZX = HN @ W^T (8192 x 1064)  -- BM=128, grid 17x64=1088 blocks
        {
            dim3 g((D_IN_PROJ + 63) / 64, NTOK / 128);
            gemm_mfma<128><<<g, 128, 0, stream>>>(
                HNh, HNl, WIH + (size_t)i * D_IN_PROJ * D_MODEL, WIL + (size_t)i * D_IN_PROJ * D_MODEL,
                nullptr, nullptr, ZX, D_IN_PROJ, D_MODEL);
        }
        // conv + silu + dt/dA precompute (vectorized: 8192*136 conv4 + 8192*8 dt threads)
        conv_dt_kernel<<<(NTOK * (CONV_DIM / 4) + NTOK * NHEADS + 255) / 256, 256, 0, stream>>>(
            ZX, conv_w + (size_t)i * CONV_DIM * D_CONV, conv_b + i * CONV_DIM,
            dt_bias + i * NHEADS, A_log + i * NHEADS, XBCC, DTDA, dir);
        // chunked SSM scan: local -> combine -> fix
        scan_local_kernel<<<BATCH * NHEADS * NCH, 1024, 0, stream>>>(
            DTDA, XBCC, Dvec + i * NHEADS, YSSM, HEND, PF, dir);
        scan_combine_kernel<<<BATCH * NHEADS, 1024, 0, stream>>>(HEND, PF, HIN);
        scan_fix_kernel<<<BATCH * NHEADS * (NCH - 1), 1024, 0, stream>>>(
            HIN, PF, XBCC, YSSM, dir);
        // gated RMSNorm -> packed
        gated_rms_kernel<<<NTOK, 512, 0, stream>>>(YSSM, ZX, ssm_norm_w + i * D_INNER, YSh, YSl);
        // out_proj + residual add (RES += YS @ W^T) -- BM=64, grid 4x128=512 blocks
        {
            dim3 g(D_MODEL / 64, NTOK / 64);
            gemm_mfma<64><<<g, 128, 0, stream>>>(
                YSh, YSl, WOH + (size_t)i * D_MODEL * D_INNER, WOL + (size_t)i * D_MODEL * D_INNER,
                nullptr, RES, RES, D_MODEL, D_INNER);
        }
        // norm2 -> packed
        add_ln_kernel<<<NTOK, 256, 0, stream>>>(
            RES, nullptr, nullptr, HNh, HNl, nullptr,
            norm2_w + i * D_MODEL, norm2_b + i * D_MODEL);
        // fc1 -> YY f32 -- BM=64, grid 8x128=1024 blocks
        {
            dim3 g((2 * D_INT) / 64, NTOK / 64);
            gemm_mfma<64><<<g, 128, 0, stream>>>(
                HNh, HNl, W1H + (size_t)i * 2 * D_INT * D_MODEL, W1L + (size_t)i * 2 * D_INT * D_MODEL,
                fc1_b + i * 2 * D_INT, nullptr, YY, 2 * D_INT, D_MODEL);
        }
        // GLU -> packed
        glu_kernel<<<(NTOK * D_INT) / 256, 256, 0, stream>>>(YY, GLh, GLl);
        // fc2 -> H -- BM=64, grid 4x128=512 blocks
        {
            dim3 g(D_MODEL / 64, NTOK / 64);
            gemm_mfma<64><<<g, 128, 0, stream>>>(
                GLh, GLl, W2H + (size_t)i * D_MODEL * D_INT, W2L + (size_t)i * D_MODEL * D_INT,
                fc2_b + i * D_MODEL, nullptr, H, D_MODEL, D_INT);
        }
    }

    // final: residual = H + RES; HNF = LNf(residual) (f32 only)
    add_ln_kernel<<<NTOK, 256, 0, stream>>>(
        H, RES, nullptr, nullptr, nullptr, HNF, normf_w, normf_b);
    zero_mean_kernel<<<(BATCH * D_MODEL + 255) / 256, 256, 0, stream>>>(MEAN);
    mean_kernel<<<BATCH * 16, 256, 0, stream>>>(HNF, MEAN);
    logits_kernel<<<1, 128, 0, stream>>>(MEAN, fc_w, fc_b, out);
}

// Round 6
// 1323.904 us; speedup vs baseline: 1.0721x; 1.0721x over previous
//
#include <hip/hip_runtime.h>
#include <math.h>

#define NLAYERS   4
#define D_MODEL   256
#define D_INNER   512
#define D_STATE   16
#define NHEADS    8
#define HEADDIM   64
#define D_CONV    4
#define D_INT     256
#define NCLS      10
#define IN_FEAT   64
#define T_LEN     1024
#define BATCH     8
#define D_IN_PROJ 1064   // 2*512 + 2*16 + 8
#define CONV_DIM  544    // 512 + 32
#define EPS       1e-5f
#define NTOK      (BATCH*T_LEN)   // 8192
#define QCH       64             // scan chunk length
#define NCH       (T_LEN/QCH)    // 16 chunks

typedef __attribute__((ext_vector_type(8))) short bf16x8;
typedef __attribute__((ext_vector_type(4))) float f32x4;

__device__ __forceinline__ float silu_f(float x) { return x / (1.f + expf(-x)); }
__device__ __forceinline__ float softplus_f(float x) { return x > 20.f ? x : log1pf(expf(x)); }

// ---- async global->LDS 16B DMA (dest must be wave-uniform base + lane*16) ----
typedef __attribute__((address_space(3))) void       lds_void_t;
typedef __attribute__((address_space(1))) const void gbl_void_t;
__device__ __forceinline__ void gload16(void* lds, const void* g) {
    __builtin_amdgcn_global_load_lds((gbl_void_t*)g, (lds_void_t*)lds, 16, 0, 0);
}

// ---- fp32 -> bf16 (RNE) split helpers ----
__device__ __forceinline__ unsigned short f2bf(float f) {
    unsigned u = __float_as_uint(f);
    return (unsigned short)((u + 0x7fffu + ((u >> 16) & 1u)) >> 16);
}
__device__ __forceinline__ float bf2f(unsigned short h) {
    return __uint_as_float((unsigned)h << 16);
}
__device__ __forceinline__ ushort2 split2(float f) {
    unsigned short hi = f2bf(f);
    unsigned short lo = f2bf(f - bf2f(hi));
    return make_ushort2(hi, lo);
}

// ---- block reduction: NW waves of 64 lanes ----
template<int NW>
__device__ __forceinline__ float block_sum(float v, float* red) {
#pragma unroll
    for (int off = 32; off > 0; off >>= 1) v += __shfl_down(v, off, 64);
    int lane = threadIdx.x & 63, wid = threadIdx.x >> 6;
    __syncthreads();
    if (lane == 0) red[wid] = v;
    __syncthreads();
    float s = 0.f;
#pragma unroll
    for (int i = 0; i < NW; ++i) s += red[i];
    return s;
}

// ---- weight pack: fp32 -> (hi,lo) bf16, vectorized ----
__global__ __launch_bounds__(256) void pack_split_kernel(
    const float* __restrict__ src, unsigned short* __restrict__ hi,
    unsigned short* __restrict__ lo, int n4)
{
    int i = blockIdx.x * 256 + threadIdx.x;
    if (i >= n4) return;
    float4 v = ((const float4*)src)[i];
    ushort2 a = split2(v.x), b = split2(v.y), c = split2(v.z), d = split2(v.w);
    ((ushort4*)hi)[i] = make_ushort4(a.x, b.x, c.x, d.x);
    ((ushort4*)lo)[i] = make_ushort4(a.y, b.y, c.y, d.y);
}

// ---- input projection: h[b,t,d] = sum_f x[b,f,t]*W[d,f] + bias[d] ----
__global__ __launch_bounds__(256) void input_proj_kernel(
    const float* __restrict__ x, const float* __restrict__ w,
    const float* __restrict__ bias, float* __restrict__ h)
{
    int bt = blockIdx.x;
    int b = bt / T_LEN, t = bt % T_LEN;
    __shared__ float xs[IN_FEAT];
    int tid = threadIdx.x;
    if (tid < IN_FEAT) xs[tid] = x[(b * IN_FEAT + tid) * T_LEN + t];
    __syncthreads();
    float acc = bias[tid];
    const float4* wr = (const float4*)(w + tid * IN_FEAT);
#pragma unroll 4
    for (int f4 = 0; f4 < IN_FEAT / 4; ++f4) {
        float4 wv = wr[f4];
        acc += xs[f4 * 4 + 0] * wv.x + xs[f4 * 4 + 1] * wv.y +
               xs[f4 * 4 + 2] * wv.z + xs[f4 * 4 + 3] * wv.w;
    }
    h[bt * D_MODEL + tid] = acc;
}

// ---- fused (optional add) + LayerNorm over 256, writes packed hi/lo and/or f32 ----
__global__ __launch_bounds__(256) void add_ln_kernel(
    const float* __restrict__ a, const float* __restrict__ b,
    float* __restrict__ sum_out, unsigned short* __restrict__ hi,
    unsigned short* __restrict__ lo, float* __restrict__ f32out,
    const float* __restrict__ w, const float* __restrict__ bias)
{
    __shared__ float red[4];
    int row = blockIdx.x, d = threadIdx.x;
    size_t o = (size_t)row * D_MODEL + d;
    float v = a[o];
    if (b) v += b[o];
    if (sum_out) sum_out[o] = v;
    float mean = block_sum<4>(v, red) * (1.f / D_MODEL);
    float xc = v - mean;
    float var = block_sum<4>(xc * xc, red) * (1.f / D_MODEL);
    float r = xc * rsqrtf(var + EPS) * w[d] + bias[d];
    if (hi) { ushort2 s = split2(r); hi[o] = s.x; lo[o] = s.y; }
    if (f32out) f32out[o] = r;
}

// ---- MFMA GEMM (unchanged from round 5, verified): C = A@W^T (+bias)(+resid)
template<int BM>
__global__ __launch_bounds__(128) void gemm_mfma(
    const unsigned short* __restrict__ Ahi, const unsigned short* __restrict__ Alo,
    const unsigned short* __restrict__ Whi, const unsigned short* __restrict__ Wlo,
    const float* __restrict__ bias, const float* __restrict__ resid,
    float* __restrict__ C, int N, int K)
{
    constexpr int MFRAG   = BM / 32;
    constexpr int AROUNDS = BM / 32;
    __shared__ unsigned short sAh[BM * 32], sAl[BM * 32];
    __shared__ unsigned short sBh[64 * 32], sBl[64 * 32];
    const int tid = threadIdx.x;
    const int lane = tid & 63, wm = tid >> 6;
    const int m0 = blockIdx.y * BM, n0 = blockIdx.x * 64;

    const int srow = tid >> 2;
    const int sk   = (tid & 3) * 8;
    const unsigned short* gAh = Ahi + (size_t)(m0 + srow) * K + sk;
    const unsigned short* gAl = Alo + (size_t)(m0 + srow) * K + sk;
    int bn  = n0 + srow;      if (bn  > N - 1) bn  = N - 1;
    int bn2 = n0 + 32 + srow; if (bn2 > N - 1) bn2 = N - 1;
    const unsigned short* gBh  = Whi + (size_t)bn  * K + sk;
    const unsigned short* gBh2 = Whi + (size_t)bn2 * K + sk;
    const unsigned short* gBl  = Wlo + (size_t)bn  * K + sk;
    const unsigned short* gBl2 = Wlo + (size_t)bn2 * K + sk;
    const size_t rK32 = (size_t)32 * K;

    const int fr = lane & 15, kg = lane >> 4;
    const int abase = (wm * (BM / 2) + fr) * 32 + kg * 8;
    const int bbase = fr * 32 + kg * 8;

    f32x4 acc[MFRAG][4] = {};

    for (int k0 = 0; k0 < K; k0 += 32) {
#pragma unroll
        for (int rr = 0; rr < AROUNDS; ++rr) {
            gload16(&sAh[tid * 8 + rr * 1024], gAh + (size_t)rr * rK32);
            gload16(&sAl[tid * 8 + rr * 1024], gAl + (size_t)rr * rK32);
        }
        gload16(&sBh[tid * 8],        gBh);
        gload16(&sBh[tid * 8 + 1024], gBh2);
        gload16(&sBl[tid * 8],        gBl);
        gload16(&sBl[tid * 8 + 1024], gBl2);
        gAh += 32; gAl += 32; gBh += 32; gBh2 += 32; gBl += 32; gBl2 += 32;
        __syncthreads();

        bf16x8 ah[MFRAG], al[MFRAG], bh[4], bl[4];
#pragma unroll
        for (int fm = 0; fm < MFRAG; ++fm) {
            ah[fm] = *(const bf16x8*)&sAh[abase + fm * 512];
            al[fm] = *(const bf16x8*)&sAl[abase + fm * 512];
        }
#pragma unroll
        for (int fn = 0; fn < 4; ++fn) {
            bh[fn] = *(const bf16x8*)&sBh[bbase + fn * 512];
            bl[fn] = *(const bf16x8*)&sBl[bbase + fn * 512];
        }
#pragma unroll
        for (int fm = 0; fm < MFRAG; ++fm)
#pragma unroll
            for (int fn = 0; fn < 4; ++fn) {
                acc[fm][fn] = __builtin_amdgcn_mfma_f32_16x16x32_bf16(ah[fm], bh[fn], acc[fm][fn], 0, 0, 0);
                acc[fm][fn] = __builtin_amdgcn_mfma_f32_16x16x32_bf16(ah[fm], bl[fn], acc[fm][fn], 0, 0, 0);
                acc[fm][fn] = __builtin_amdgcn_mfma_f32_16x16x32_bf16(al[fm], bh[fn], acc[fm][fn], 0, 0, 0);
            }
        __syncthreads();
    }

    const int orow0 = kg * 4;
#pragma unroll
    for (int fm = 0; fm < MFRAG; ++fm)
#pragma unroll
        for (int fn = 0; fn < 4; ++fn) {
            int n = n0 + fn * 16 + fr;
            if (n < N) {
                float bv = bias ? bias[n] : 0.f;
#pragma unroll
                for (int r = 0; r < 4; ++r) {
                    int m = m0 + wm * (BM / 2) + fm * 16 + orow0 + r;
                    size_t off = (size_t)m * N + n;
                    float v = acc[fm][fn][r] + bv;
                    if (resid) v += resid[off];
                    C[off] = v;
                }
            }
        }
}

// ---- depthwise causal conv (K=4) + silu (float4 over channels), fused dt/dA ----
__global__ __launch_bounds__(256) void conv_dt_kernel(
    const float* __restrict__ zx, const float* __restrict__ cw,
    const float* __restrict__ cb, const float* __restrict__ dt_bias,
    const float* __restrict__ A_log, float* __restrict__ out,
    float2* __restrict__ dtda, int dir)
{
    const int NCG = CONV_DIM / 4;   // 136
    int idx = blockIdx.x * 256 + threadIdx.x;
    if (idx < NTOK * NCG) {
        int cg = idx % NCG;
        int bt = idx / NCG;
        int c = cg * 4;
        int s = bt % T_LEN, b = bt / T_LEN;
        float4 acc = *(const float4*)(cb + c);
        float4 w0 = *(const float4*)(cw + (c + 0) * 4);
        float4 w1 = *(const float4*)(cw + (c + 1) * 4);
        float4 w2 = *(const float4*)(cw + (c + 2) * 4);
        float4 w3 = *(const float4*)(cw + (c + 3) * 4);
#pragma unroll
        for (int k = 0; k < D_CONV; ++k) {
            int sj = s + k - (D_CONV - 1);
            if (sj >= 0) {
                int t = dir ? (T_LEN - 1 - sj) : sj;
                float4 xv = *(const float4*)(zx + ((size_t)(b * T_LEN + t)) * D_IN_PROJ + D_INNER + c);
                acc.x += xv.x * (&w0.x)[k];
                acc.y += xv.y * (&w1.x)[k];
                acc.z += xv.z * (&w2.x)[k];
                acc.w += xv.w * (&w3.x)[k];
            }
        }
        int tout = dir ? (T_LEN - 1 - s) : s;
        float4 r = make_float4(silu_f(acc.x), silu_f(acc.y), silu_f(acc.z), silu_f(acc.w));
        *(float4*)(out + ((size_t)(b * T_LEN + tout)) * CONV_DIM + c) = r;
    } else {
        int j = idx - NTOK * NCG;
        if (j < NTOK * NHEADS) {
            int bt = j >> 3, h = j & 7;
            float dtraw = zx[(size_t)bt * D_IN_PROJ + (D_IN_PROJ - NHEADS) + h] + dt_bias[h];
            float dt = softplus_f(dtraw);
            float Ac = -expf(A_log[h]);
            dtda[(size_t)bt * NHEADS + h] = make_float2(dt, expf(dt * Ac));
        }
    }
}

// ==== chunked SSM scan (dA scalar per head => linear chunk combine) ====
// S1 v2: bulk-coalesced LDS staging; serial recurrence runs from LDS only;
// y buffered in LDS and bulk-written with float4.
__global__ __launch_bounds__(1024) void scan_local_kernel(
    const float2* __restrict__ dtda, const float* __restrict__ xbc,
    const float* __restrict__ Dvec, float* __restrict__ y,
    float* __restrict__ hend, float* __restrict__ pf, int dir)
{
    __shared__ float  sx[QCH][HEADDIM];   // 16 KB
    __shared__ float  sBC[QCH][32];       //  8 KB (B | C contiguous)
    __shared__ float  sy[QCH][HEADDIM];   // 16 KB
    __shared__ float2 sd[QCH];            // 512 B
    __shared__ float  spf[QCH];           // 256 B
    int bx = blockIdx.x;                  // 1024 = B*H*NCH
    int c = bx & (NCH - 1), h = (bx >> 4) & 7, b = bx >> 7;
    int tid = threadIdx.x, p = tid >> 4, n = tid & 15;
    int s0 = c * QCH;
    // --- bulk load: x (1024 float4), B|C (512 float4), dtda (64 float2) ---
    {
        int si = tid >> 4, l4 = (tid & 15) * 4;
        int s = s0 + si; int t = dir ? (T_LEN - 1 - s) : s;
        size_t row = (size_t)b * T_LEN + t;
        *(float4*)&sx[si][l4] = *(const float4*)(xbc + row * CONV_DIM + h * HEADDIM + l4);
    }
    if (tid < 512) {
        int si = tid >> 3, l4 = (tid & 7) * 4;
        int s = s0 + si; int t = dir ? (T_LEN - 1 - s) : s;
        size_t row = (size_t)b * T_LEN + t;
        *(float4*)&sBC[si][l4] = *(const float4*)(xbc + row * CONV_DIM + D_INNER + l4);
    }
    if (tid < QCH) {
        int s = s0 + tid; int t = dir ? (T_LEN - 1 - s) : s;
        sd[tid] = dtda[((size_t)b * T_LEN + t) * NHEADS + h];
    }
    __syncthreads();
    // --- serial recurrence from LDS ---
    float Dh = Dvec[h];
    float hreg = 0.f, pp = 1.f;
    for (int si = 0; si < QCH; ++si) {
        float2 dd = sd[si];
        float xv = sx[si][p];
        float Bv = sBC[si][n];
        float Cv = sBC[si][16 + n];
        hreg = hreg * dd.y + (dd.x * xv) * Bv;
        pp *= dd.y;
        float yv = hreg * Cv;
        yv += __shfl_xor(yv, 1, 16);
        yv += __shfl_xor(yv, 2, 16);
        yv += __shfl_xor(yv, 4, 16);
        yv += __shfl_xor(yv, 8, 16);
        if (n == 0) sy[si][p] = yv + Dh * xv;
        if (tid == 0) spf[si] = pp;
    }
    __syncthreads();
    // --- bulk write: y (float4 coalesced), pf, hend ---
    {
        int si = tid >> 4, l4 = (tid & 15) * 4;
        int s = s0 + si; int t = dir ? (T_LEN - 1 - s) : s;
        size_t row = (size_t)b * T_LEN + t;
        *(float4*)(y + row * D_INNER + h * HEADDIM + l4) = *(float4*)&sy[si][l4];
    }
    if (tid < QCH) pf[((size_t)(b * NHEADS + h)) * T_LEN + s0 + tid] = spf[tid];
    hend[((size_t)((b * NHEADS + h) * NCH + c)) * 1024 + tid] = hreg;
}

// S2: prefix over chunks for 65536 independent series; regridded for CU coverage.
__global__ __launch_bounds__(256) void scan_combine_kernel(
    const float* __restrict__ hend, const float* __restrict__ pf,
    float* __restrict__ hin_out)
{
    int e = blockIdx.x * 256 + threadIdx.x;   // 0..65535
    int base = e >> 10, tid = e & 1023;
    float hin = 0.f;
    for (int c = 0; c < NCH; ++c) {
        hin_out[((size_t)base * NCH + c) * 1024 + tid] = hin;
        float Pc = pf[(size_t)base * T_LEN + c * QCH + (QCH - 1)];
        hin = hend[((size_t)base * NCH + c) * 1024 + tid] + Pc * hin;
    }
}

// S3 v2: correction via LDS; y updated with one coalesced float4 RMW pass.
__global__ __launch_bounds__(1024) void scan_fix_kernel(
    const float* __restrict__ hin_in, const float* __restrict__ pf,
    const float* __restrict__ xbc, float* __restrict__ y, int dir)
{
    __shared__ float sC[QCH][16];          // 4 KB
    __shared__ float spf[QCH];             // 256 B
    __shared__ float sco[QCH][HEADDIM];    // 16 KB
    int c = 1 + (blockIdx.x % (NCH - 1));
    int bh = blockIdx.x / (NCH - 1);
    int b = bh >> 3, h = bh & 7;
    int tid = threadIdx.x, p = tid >> 4, n = tid & 15;
    size_t base = (size_t)(b * NHEADS + h);
    int s0 = c * QCH;
    float hin = hin_in[(base * NCH + c) * 1024 + tid];
    // --- bulk load C (256 float4) and pf (64) ---
    if (tid < 256) {
        int si = tid >> 2, l4 = (tid & 3) * 4;
        int s = s0 + si; int t = dir ? (T_LEN - 1 - s) : s;
        size_t row = (size_t)b * T_LEN + t;
        *(float4*)&sC[si][l4] = *(const float4*)(xbc + row * CONV_DIM + D_INNER + D_STATE + l4);
    }
    if (tid < QCH) spf[tid] = pf[base * T_LEN + s0 + tid];
    __syncthreads();
    // --- correction loop, all-LDS ---
    for (int si = 0; si < QCH; ++si) {
        float v = hin * sC[si][n];
        v += __shfl_xor(v, 1, 16);
        v += __shfl_xor(v, 2, 16);
        v += __shfl_xor(v, 4, 16);
        v += __shfl_xor(v, 8, 16);
        if (n == 0) sco[si][p] = spf[si] * v;
    }
    __syncthreads();
    // --- coalesced float4 RMW of y ---
    {
        int si = tid >> 4, l4 = (tid & 15) * 4;
        int s = s0 + si; int t = dir ? (T_LEN - 1 - s) : s;
        size_t row = (size_t)b * T_LEN + t;
        float4* yp = (float4*)(y + row * D_INNER + h * HEADDIM + l4);
        float4 yv = *yp;
        float4 cv = *(float4*)&sco[si][l4];
        yv.x += cv.x; yv.y += cv.y; yv.z += cv.z; yv.w += cv.w;
        *yp = yv;
    }
}

// ---- gated RMSNorm over 512, writes packed hi/lo ----
__global__ __launch_bounds__(512) void gated_rms_kernel(
    const float* __restrict__ y, const float* __restrict__ zx,
    const float* __restrict__ w, unsigned short* __restrict__ hi,
    unsigned short* __restrict__ lo)
{
    __shared__ float red[8];
    int row = blockIdx.x, d = threadIdx.x;
    float z = zx[(size_t)row * D_IN_PROJ + d];
    float v = y[(size_t)row * D_INNER + d] * silu_f(z);
    float ss = block_sum<8>(v * v, red);
    float r = rsqrtf(ss * (1.f / D_INNER) + EPS);
    float o = v * r * w[d];
    ushort2 s = split2(o);
    size_t off = (size_t)row * D_INNER + d;
    hi[off] = s.x; lo[off] = s.y;
}

// ---- GLU: g = y1 * silu(gate), writes packed hi/lo ----
__global__ __launch_bounds__(256) void glu_kernel(
    const float* __restrict__ yy, unsigned short* __restrict__ hi,
    unsigned short* __restrict__ lo)
{
    int idx = blockIdx.x * 256 + threadIdx.x;
    int m = idx >> 8, j = idx & 255;
    float v = yy[(size_t)m * (2 * D_INT) + j] * silu_f(yy[(size_t)m * (2 * D_INT) + D_INT + j]);
    ushort2 s = split2(v);
    hi[idx] = s.x; lo[idx] = s.y;
}

// ---- final mean over T + logits ----
__global__ void zero_mean_kernel(float* mean) {
    int i = blockIdx.x * 256 + threadIdx.x;
    if (i < BATCH * D_MODEL) mean[i] = 0.f;
}
__global__ __launch_bounds__(256) void mean_kernel(
    const float* __restrict__ hn, float* __restrict__ mean)
{
    int b = blockIdx.x >> 4;
    int slab = blockIdx.x & 15;
    int d = threadIdx.x;
    float s = 0.f;
    int t0 = slab * 64;
    for (int t = t0; t < t0 + 64; ++t) s += hn[((size_t)(b * T_LEN + t)) * D_MODEL + d];
    atomicAdd(&mean[b * D_MODEL + d], s * (1.f / T_LEN));
}
__global__ void logits_kernel(const float* __restrict__ mean,
                              const float* __restrict__ fcw,
                              const float* __restrict__ fcb,
                              float* __restrict__ out)
{
    int tid = threadIdx.x;
    if (tid < BATCH * NCLS) {
        int b = tid / NCLS, c = tid % NCLS;
        float s = fcb[c];
        for (int d = 0; d < D_MODEL; ++d) s += mean[b * D_MODEL + d] * fcw[c * D_MODEL + d];
        out[tid] = s;
    }
}

extern "C" void kernel_launch(void* const* d_in, const int* in_sizes, int n_in,
                              void* d_out, int out_size, void* d_ws, size_t ws_size,
                              hipStream_t stream)
{
    const float* x            = (const float*)d_in[0];
    const float* input_proj_w = (const float*)d_in[1];
    const float* input_proj_b = (const float*)d_in[2];
    const float* norm1_w      = (const float*)d_in[3];
    const float* norm1_b      = (const float*)d_in[4];
    const float* in_proj_w    = (const float*)d_in[5];
    const float* conv_w       = (const float*)d_in[6];
    const float* conv_b       = (const float*)d_in[7];
    const float* dt_bias      = (const float*)d_in[8];
    const float* A_log        = (const float*)d_in[9];
    const float* Dvec         = (const float*)d_in[10];
    const float* ssm_norm_w   = (const float*)d_in[11];
    const float* out_proj_w   = (const float*)d_in[12];
    const float* norm2_w      = (const float*)d_in[13];
    const float* norm2_b      = (const float*)d_in[14];
    const float* fc1_w        = (const float*)d_in[15];
    const float* fc1_b        = (const float*)d_in[16];
    const float* fc2_w        = (const float*)d_in[17];
    const float* fc2_b        = (const float*)d_in[18];
    const float* normf_w      = (const float*)d_in[19];
    const float* normf_b      = (const float*)d_in[20];
    const float* fc_w         = (const float*)d_in[21];
    const float* fc_b         = (const float*)d_in[22];
    float* out = (float*)d_out;

    char* ws = (char*)d_ws;
    float*          RES  = (float*)(ws + 0);                 // 8 MB fp32 8192x256
    float*          H    = (float*)(ws + 8388608);           // 8 MB
    unsigned short* HNh  = (unsigned short*)(ws + 16777216); // 4 MB bf16 8192x256
    unsigned short* HNl  = (unsigned short*)(ws + 20971520); // 4 MB
    float*          ZX   = (float*)(ws + 25165824);          // 33.25 MB fp32 8192x1064
    float*          XBCC = (float*)(ws + 60030976);          // 17 MB fp32 8192x544
    float*          YSSM = (float*)(ws + 77856768);          // 16 MB fp32 8192x512
    unsigned short* YSh  = (unsigned short*)(ws + 94633984); // 8 MB bf16 8192x512
    unsigned short* YSl  = (unsigned short*)(ws + 103022592);// 8 MB
    unsigned short* GLh  = (unsigned short*)(ws + 111411200);// 4 MB bf16 8192x256
    unsigned short* GLl  = (unsigned short*)(ws + 115605504);// 4 MB
    unsigned short* WIH  = (unsigned short*)(ws + 119799808);// 2.08 MB 4x1064x256
    unsigned short* WIL  = (unsigned short*)(ws + 121978880);
    unsigned short* WOH  = (unsigned short*)(ws + 124157952);// 1 MB 4x256x512
    unsigned short* WOL  = (unsigned short*)(ws + 125206528);
    unsigned short* W1H  = (unsigned short*)(ws + 126255104);// 1 MB 4x512x256
    unsigned short* W1L  = (unsigned short*)(ws + 127303680);
    unsigned short* W2H  = (unsigned short*)(ws + 128352256);// 0.5 MB 4x256x256
    unsigned short* W2L  = (unsigned short*)(ws + 128876544);
    float2*         DTDA = (float2*)(ws + 129400832);        // 0.5 MB 8192x8 float2
    float*          MEAN = (float*)(ws + 129925120);         // 8 KB
    float*          YY   = ZX;                 // alias: fc1 f32 out in dead ZX
    float*          HNF  = XBCC;               // alias: final LN f32 out in dead XBCC
    // scan scratch aliased into regions dead during the scan phase:
    float*          PF   = (float*)(ws + 16777216);  // 256 KB in HNh (HN dead conv..norm2)
    float*          HEND = (float*)(ws + 111411200); // 4 MB in GLh (GL dead during scan)
    float*          HIN  = (float*)(ws + 115605504); // 4 MB in GLl

    // pack all layers' weights to bf16 hi/lo (once per call)
    pack_split_kernel<<<1064, 256, 0, stream>>>(in_proj_w,  WIH, WIL, NLAYERS * D_IN_PROJ * D_MODEL / 4);
    pack_split_kernel<<<512,  256, 0, stream>>>(out_proj_w, WOH, WOL, NLAYERS * D_MODEL * D_INNER / 4);
    pack_split_kernel<<<512,  256, 0, stream>>>(fc1_w,      W1H, W1L, NLAYERS * 2 * D_INT * D_MODEL / 4);
    pack_split_kernel<<<256,  256, 0, stream>>>(fc2_w,      W2H, W2L, NLAYERS * D_MODEL * D_INT / 4);

    input_proj_kernel<<<NTOK, 256, 0, stream>>>(x, input_proj_w, input_proj_b, H);

    for (int i = 0; i < NLAYERS; ++i) {
        int dir = i & 1;   // odd layers: reversed-time conv+scan (flip trick)
        // residual = H (+ RES); HN = LN1(residual), packed
        add_ln_kernel<<<NTOK, 256, 0, stream>>>(
            H, i ? RES : nullptr, RES, HNh, HNl, nullptr,
            norm1_w + i * D_MODEL, norm1_b + i * D_MODEL);
        // in_proj: ZX = HN @ W^T (8192 x 1064)  -- BM=128
        {
            dim3 g((D_IN_PROJ + 63) / 64, NTOK / 128);
            gemm_mfma<128><<<g, 128, 0, stream>>>(
                HNh, HNl, WIH + (size_t)i * D_IN_PROJ * D_MODEL, WIL + (size_t)i * D_IN_PROJ * D_MODEL,
                nullptr, nullptr, ZX, D_IN_PROJ, D_MODEL);
        }
        // conv + silu + dt/dA precompute
        conv_dt_kernel<<<(NTOK * (CONV_DIM / 4) + NTOK * NHEADS + 255) / 256, 256, 0, stream>>>(
            ZX, conv_w + (size_t)i * CONV_DIM * D_CONV, conv_b + i * CONV_DIM,
            dt_bias + i * NHEADS, A_log + i * NHEADS, XBCC, DTDA, dir);
        // chunked SSM scan: local -> combine -> fix
        scan_local_kernel<<<BATCH * NHEADS * NCH, 1024, 0, stream>>>(
            DTDA, XBCC, Dvec + i * NHEADS, YSSM, HEND, PF, dir);
        scan_combine_kernel<<<BATCH * NHEADS * 1024 / 256, 256, 0, stream>>>(HEND, PF, HIN);
        scan_fix_kernel<<<BATCH * NHEADS * (NCH - 1), 1024, 0, stream>>>(
            HIN, PF, XBCC, YSSM, dir);
        // gated RMSNorm -> packed
        gated_rms_kernel<<<NTOK, 512, 0, stream>>>(YSSM, ZX, ssm_norm_w + i * D_INNER, YSh, YSl);
        // out_proj + residual add (RES += YS @ W^T) -- BM=64
        {
            dim3 g(D_MODEL / 64, NTOK / 64);
            gemm_mfma<64><<<g, 128, 0, stream>>>(
                YSh, YSl, WOH + (size_t)i * D_MODEL * D_INNER, WOL + (size_t)i * D_MODEL * D_INNER,
                nullptr, RES, RES, D_MODEL, D_INNER);
        }
        // norm2 -> packed
        add_ln_kernel<<<NTOK, 256, 0, stream>>>(
            RES, nullptr, nullptr, HNh, HNl, nullptr,
            norm2_w + i * D_MODEL, norm2_b + i * D_MODEL);
        // fc1 -> YY f32 -- BM=64
        {
            dim3 g((2 * D_INT) / 64, NTOK / 64);
            gemm_mfma<64><<<g, 128, 0, stream>>>(
                HNh, HNl, W1H + (size_t)i * 2 * D_INT * D_MODEL, W1L + (size_t)i * 2 * D_INT * D_MODEL,
                fc1_b + i * 2 * D_INT, nullptr, YY, 2 * D_INT, D_MODEL);
        }
        // GLU -> packed
        glu_kernel<<<(NTOK * D_INT) / 256, 256, 0, stream>>>(YY, GLh, GLl);
        // fc2 -> H -- BM=64
        {
            dim3 g(D_MODEL / 64, NTOK / 64);
            gemm_mfma<64><<<g, 128, 0, stream>>>(
                GLh, GLl, W2H + (size_t)i * D_MODEL * D_INT, W2L + (size_t)i * D_MODEL * D_INT,
                fc2_b + i * D_MODEL, nullptr, H, D_MODEL, D_INT);
        }
    }

    // final: residual = H + RES; HNF = LNf(residual) (f32 only)
    add_ln_kernel<<<NTOK, 256, 0, stream>>>(
        H, RES, nullptr, nullptr, nullptr, HNF, normf_w, normf_b);
    zero_mean_kernel<<<(BATCH * D_MODEL + 255) / 256, 256, 0, stream>>>(MEAN);
    mean_kernel<<<BATCH * 16, 256, 0, stream>>>(HNF, MEAN);
    logits_kernel<<<1, 128, 0, stream>>>(MEAN, fc_w, fc_b, out);
}

// Round 9
// 866.705 us; speedup vs baseline: 1.6376x; 1.5275x over previous
//
#include <hip/hip_runtime.h>
#include <math.h>

#define NLAYERS   4
#define D_MODEL   256
#define D_INNER   512
#define D_STATE   16
#define NHEADS    8
#define HEADDIM   64
#define D_CONV    4
#define D_INT     256
#define NCLS      10
#define IN_FEAT   64
#define T_LEN     1024
#define BATCH     8
#define D_IN_PROJ 1064   // 2*512 + 2*16 + 8
#define CONV_DIM  544    // 512 + 32
#define EPS       1e-5f
#define NTOK      (BATCH*T_LEN)   // 8192
#define QCH       32             // scan chunk length
#define NCH       (T_LEN/QCH)    // 32 chunks

typedef __attribute__((ext_vector_type(8))) short bf16x8;
typedef __attribute__((ext_vector_type(4))) float f32x4;

__device__ __forceinline__ float silu_f(float x) { return x / (1.f + expf(-x)); }
__device__ __forceinline__ float softplus_f(float x) { return x > 20.f ? x : log1pf(expf(x)); }

// ---- async global->LDS 16B DMA (dest must be wave-uniform base + lane*16) ----
typedef __attribute__((address_space(3))) void       lds_void_t;
typedef __attribute__((address_space(1))) const void gbl_void_t;
__device__ __forceinline__ void gload16(void* lds, const void* g) {
    __builtin_amdgcn_global_load_lds((gbl_void_t*)g, (lds_void_t*)lds, 16, 0, 0);
}

// ---- fp32 -> bf16 (RNE) split helpers ----
__device__ __forceinline__ unsigned short f2bf(float f) {
    unsigned u = __float_as_uint(f);
    return (unsigned short)((u + 0x7fffu + ((u >> 16) & 1u)) >> 16);
}
__device__ __forceinline__ float bf2f(unsigned short h) {
    return __uint_as_float((unsigned)h << 16);
}
__device__ __forceinline__ ushort2 split2(float f) {
    unsigned short hi = f2bf(f);
    unsigned short lo = f2bf(f - bf2f(hi));
    return make_ushort2(hi, lo);
}

// ---- block reduction: NW waves of 64 lanes ----
template<int NW>
__device__ __forceinline__ float block_sum(float v, float* red) {
#pragma unroll
    for (int off = 32; off > 0; off >>= 1) v += __shfl_down(v, off, 64);
    int lane = threadIdx.x & 63, wid = threadIdx.x >> 6;
    __syncthreads();
    if (lane == 0) red[wid] = v;
    __syncthreads();
    float s = 0.f;
#pragma unroll
    for (int i = 0; i < NW; ++i) s += red[i];
    return s;
}

// ---- weight pack: fp32 -> (hi,lo) bf16, vectorized ----
__global__ __launch_bounds__(256) void pack_split_kernel(
    const float* __restrict__ src, unsigned short* __restrict__ hi,
    unsigned short* __restrict__ lo, int n4)
{
    int i = blockIdx.x * 256 + threadIdx.x;
    if (i >= n4) return;
    float4 v = ((const float4*)src)[i];
    ushort2 a = split2(v.x), b = split2(v.y), c = split2(v.z), d = split2(v.w);
    ((ushort4*)hi)[i] = make_ushort4(a.x, b.x, c.x, d.x);
    ((ushort4*)lo)[i] = make_ushort4(a.y, b.y, c.y, d.y);
}

// ---- fc1 pack with row reorder for fused GLU:
// new row r (in [0,512) per layer): x=r/64, i=r%64;
// orig = i<32 ? x*32+i  (y1 col)  :  256 + x*32 + (i-32)  (gate col)
__global__ __launch_bounds__(256) void pack_fc1_kernel(
    const float* __restrict__ src, unsigned short* __restrict__ hi,
    unsigned short* __restrict__ lo, int n4)
{
    int i4 = blockIdx.x * 256 + threadIdx.x;
    if (i4 >= n4) return;
    int gl  = i4 / (512 * 64);          // layer
    int rem = i4 % (512 * 64);
    int r   = rem / 64;                 // reordered row
    int k4  = rem % 64;                 // float4 index in row (K=256)
    int x = r >> 6, ii = r & 63;
    int orig = (ii < 32) ? (x * 32 + ii) : (256 + x * 32 + (ii - 32));
    float4 v = ((const float4*)src)[(gl * 512 + orig) * 64 + k4];
    ushort2 a = split2(v.x), b = split2(v.y), c = split2(v.z), d = split2(v.w);
    ((ushort4*)hi)[i4] = make_ushort4(a.x, b.x, c.x, d.x);
    ((ushort4*)lo)[i4] = make_ushort4(a.y, b.y, c.y, d.y);
}

// ---- input projection: h[b,t,d] = sum_f x[b,f,t]*W[d,f] + bias[d] ----
__global__ __launch_bounds__(256) void input_proj_kernel(
    const float* __restrict__ x, const float* __restrict__ w,
    const float* __restrict__ bias, float* __restrict__ h)
{
    int bt = blockIdx.x;
    int b = bt / T_LEN, t = bt % T_LEN;
    __shared__ float xs[IN_FEAT];
    int tid = threadIdx.x;
    if (tid < IN_FEAT) xs[tid] = x[(b * IN_FEAT + tid) * T_LEN + t];
    __syncthreads();
    float acc = bias[tid];
    const float4* wr = (const float4*)(w + tid * IN_FEAT);
#pragma unroll 4
    for (int f4 = 0; f4 < IN_FEAT / 4; ++f4) {
        float4 wv = wr[f4];
        acc += xs[f4 * 4 + 0] * wv.x + xs[f4 * 4 + 1] * wv.y +
               xs[f4 * 4 + 2] * wv.z + xs[f4 * 4 + 3] * wv.w;
    }
    h[bt * D_MODEL + tid] = acc;
}

// ---- fused (optional add) + LayerNorm over 256, writes packed hi/lo and/or f32 ----
__global__ __launch_bounds__(256) void add_ln_kernel(
    const float* __restrict__ a, const float* __restrict__ b,
    float* __restrict__ sum_out, unsigned short* __restrict__ hi,
    unsigned short* __restrict__ lo, float* __restrict__ f32out,
    const float* __restrict__ w, const float* __restrict__ bias)
{
    __shared__ float red[4];
    int row = blockIdx.x, d = threadIdx.x;
    size_t o = (size_t)row * D_MODEL + d;
    float v = a[o];
    if (b) v += b[o];
    if (sum_out) sum_out[o] = v;
    float mean = block_sum<4>(v, red) * (1.f / D_MODEL);
    float xc = v - mean;
    float var = block_sum<4>(xc * xc, red) * (1.f / D_MODEL);
    float r = xc * rsqrtf(var + EPS) * w[d] + bias[d];
    if (hi) { ushort2 s = split2(r); hi[o] = s.x; lo[o] = s.y; }
    if (f32out) f32out[o] = r;
}

// ---- MFMA GEMM (verified): C = A@W^T (+bias)(+resid)
template<int BM>
__global__ __launch_bounds__(128) void gemm_mfma(
    const unsigned short* __restrict__ Ahi, const unsigned short* __restrict__ Alo,
    const unsigned short* __restrict__ Whi, const unsigned short* __restrict__ Wlo,
    const float* __restrict__ bias, const float* __restrict__ resid,
    float* __restrict__ C, int N, int K)
{
    constexpr int MFRAG   = BM / 32;
    constexpr int AROUNDS = BM / 32;
    __shared__ unsigned short sAh[BM * 32], sAl[BM * 32];
    __shared__ unsigned short sBh[64 * 32], sBl[64 * 32];
    const int tid = threadIdx.x;
    const int lane = tid & 63, wm = tid >> 6;
    const int m0 = blockIdx.y * BM, n0 = blockIdx.x * 64;

    const int srow = tid >> 2;
    const int sk   = (tid & 3) * 8;
    const unsigned short* gAh = Ahi + (size_t)(m0 + srow) * K + sk;
    const unsigned short* gAl = Alo + (size_t)(m0 + srow) * K + sk;
    int bn  = n0 + srow;      if (bn  > N - 1) bn  = N - 1;
    int bn2 = n0 + 32 + srow; if (bn2 > N - 1) bn2 = N - 1;
    const unsigned short* gBh  = Whi + (size_t)bn  * K + sk;
    const unsigned short* gBh2 = Whi + (size_t)bn2 * K + sk;
    const unsigned short* gBl  = Wlo + (size_t)bn  * K + sk;
    const unsigned short* gBl2 = Wlo + (size_t)bn2 * K + sk;
    const size_t rK32 = (size_t)32 * K;

    const int fr = lane & 15, kg = lane >> 4;
    const int abase = (wm * (BM / 2) + fr) * 32 + kg * 8;
    const int bbase = fr * 32 + kg * 8;

    f32x4 acc[MFRAG][4] = {};

    for (int k0 = 0; k0 < K; k0 += 32) {
#pragma unroll
        for (int rr = 0; rr < AROUNDS; ++rr) {
            gload16(&sAh[tid * 8 + rr * 1024], gAh + (size_t)rr * rK32);
            gload16(&sAl[tid * 8 + rr * 1024], gAl + (size_t)rr * rK32);
        }
        gload16(&sBh[tid * 8],        gBh);
        gload16(&sBh[tid * 8 + 1024], gBh2);
        gload16(&sBl[tid * 8],        gBl);
        gload16(&sBl[tid * 8 + 1024], gBl2);
        gAh += 32; gAl += 32; gBh += 32; gBh2 += 32; gBl += 32; gBl2 += 32;
        __syncthreads();

        bf16x8 ah[MFRAG], al[MFRAG], bh[4], bl[4];
#pragma unroll
        for (int fm = 0; fm < MFRAG; ++fm) {
            ah[fm] = *(const bf16x8*)&sAh[abase + fm * 512];
            al[fm] = *(const bf16x8*)&sAl[abase + fm * 512];
        }
#pragma unroll
        for (int fn = 0; fn < 4; ++fn) {
            bh[fn] = *(const bf16x8*)&sBh[bbase + fn * 512];
            bl[fn] = *(const bf16x8*)&sBl[bbase + fn * 512];
        }
#pragma unroll
        for (int fm = 0; fm < MFRAG; ++fm)
#pragma unroll
            for (int fn = 0; fn < 4; ++fn) {
                acc[fm][fn] = __builtin_amdgcn_mfma_f32_16x16x32_bf16(ah[fm], bh[fn], acc[fm][fn], 0, 0, 0);
                acc[fm][fn] = __builtin_amdgcn_mfma_f32_16x16x32_bf16(ah[fm], bl[fn], acc[fm][fn], 0, 0, 0);
                acc[fm][fn] = __builtin_amdgcn_mfma_f32_16x16x32_bf16(al[fm], bh[fn], acc[fm][fn], 0, 0, 0);
            }
        __syncthreads();
    }

    const int orow0 = kg * 4;
#pragma unroll
    for (int fm = 0; fm < MFRAG; ++fm)
#pragma unroll
        for (int fn = 0; fn < 4; ++fn) {
            int n = n0 + fn * 16 + fr;
            if (n < N) {
                float bv = bias ? bias[n] : 0.f;
#pragma unroll
                for (int r = 0; r < 4; ++r) {
                    int m = m0 + wm * (BM / 2) + fm * 16 + orow0 + r;
                    size_t off = (size_t)m * N + n;
                    float v = acc[fm][fn][r] + bv;
                    if (resid) v += resid[off];
                    C[off] = v;
                }
            }
        }
}

// ---- fc1 GEMM with fused GLU epilogue (weights pre-reordered by pack_fc1).
// Block covers reordered cols [x*64, x*64+64): fn 0,1 = y1 of logical cols
// [x*32, x*32+32), fn 2,3 = gate of the SAME cols (identical lane mapping).
// Writes g = y1*silu(gate) as packed bf16 hi/lo to GL (N_out = 256).
__global__ __launch_bounds__(128) void gemm_mfma_glu(
    const unsigned short* __restrict__ Ahi, const unsigned short* __restrict__ Alo,
    const unsigned short* __restrict__ Whi, const unsigned short* __restrict__ Wlo,
    const float* __restrict__ bias,   // original fc1_b (512 per layer)
    unsigned short* __restrict__ Ghi, unsigned short* __restrict__ Glo, int K)
{
    constexpr int BM = 64;
    __shared__ unsigned short sAh[BM * 32], sAl[BM * 32];
    __shared__ unsigned short sBh[64 * 32], sBl[64 * 32];
    const int tid = threadIdx.x;
    const int lane = tid & 63, wm = tid >> 6;
    const int m0 = blockIdx.y * BM, n0 = blockIdx.x * 64;

    const int srow = tid >> 2;
    const int sk   = (tid & 3) * 8;
    const unsigned short* gAh = Ahi + (size_t)(m0 + srow) * K + sk;
    const unsigned short* gAl = Alo + (size_t)(m0 + srow) * K + sk;
    const unsigned short* gBh  = Whi + (size_t)(n0 + srow) * K + sk;
    const unsigned short* gBh2 = Whi + (size_t)(n0 + 32 + srow) * K + sk;
    const unsigned short* gBl  = Wlo + (size_t)(n0 + srow) * K + sk;
    const unsigned short* gBl2 = Wlo + (size_t)(n0 + 32 + srow) * K + sk;
    const size_t rK32 = (size_t)32 * K;

    const int fr = lane & 15, kg = lane >> 4;
    const int abase = (wm * 32 + fr) * 32 + kg * 8;
    const int bbase = fr * 32 + kg * 8;

    f32x4 acc[2][4] = {};

    for (int k0 = 0; k0 < K; k0 += 32) {
#pragma unroll
        for (int rr = 0; rr < 2; ++rr) {
            gload16(&sAh[tid * 8 + rr * 1024], gAh + (size_t)rr * rK32);
            gload16(&sAl[tid * 8 + rr * 1024], gAl + (size_t)rr * rK32);
        }
        gload16(&sBh[tid * 8],        gBh);
        gload16(&sBh[tid * 8 + 1024], gBh2);
        gload16(&sBl[tid * 8],        gBl);
        gload16(&sBl[tid * 8 + 1024], gBl2);
        gAh += 32; gAl += 32; gBh += 32; gBh2 += 32; gBl += 32; gBl2 += 32;
        __syncthreads();

        bf16x8 ah[2], al[2], bh[4], bl[4];
#pragma unroll
        for (int fm = 0; fm < 2; ++fm) {
            ah[fm] = *(const bf16x8*)&sAh[abase + fm * 512];
            al[fm] = *(const bf16x8*)&sAl[abase + fm * 512];
        }
#pragma unroll
        for (int fn = 0; fn < 4; ++fn) {
            bh[fn] = *(const bf16x8*)&sBh[bbase + fn * 512];
            bl[fn] = *(const bf16x8*)&sBl[bbase + fn * 512];
        }
#pragma unroll
        for (int fm = 0; fm < 2; ++fm)
#pragma unroll
            for (int fn = 0; fn < 4; ++fn) {
                acc[fm][fn] = __builtin_amdgcn_mfma_f32_16x16x32_bf16(ah[fm], bh[fn], acc[fm][fn], 0, 0, 0);
                acc[fm][fn] = __builtin_amdgcn_mfma_f32_16x16x32_bf16(ah[fm], bl[fn], acc[fm][fn], 0, 0, 0);
                acc[fm][fn] = __builtin_amdgcn_mfma_f32_16x16x32_bf16(al[fm], bh[fn], acc[fm][fn], 0, 0, 0);
            }
        __syncthreads();
    }

    // fused GLU epilogue
    const int orow0 = kg * 4;
#pragma unroll
    for (int fm = 0; fm < 2; ++fm)
#pragma unroll
        for (int fn = 0; fn < 2; ++fn) {
            int lc = (n0 >> 1) + fn * 16 + fr;        // logical GL col 0..255
            float by = bias[lc], bg = bias[256 + lc];
#pragma unroll
            for (int r = 0; r < 4; ++r) {
                int m = m0 + wm * 32 + fm * 16 + orow0 + r;
                float y1 = acc[fm][fn][r] + by;
                float gt = acc[fm][fn + 2][r] + bg;
                float g  = y1 * silu_f(gt);
                ushort2 s = split2(g);
                size_t off = (size_t)m * D_INT + lc;
                Ghi[off] = s.x; Glo[off] = s.y;
            }
        }
}

// ---- depthwise causal conv (K=4) + silu (float4 over channels), fused dt/dA ----
__global__ __launch_bounds__(256) void conv_dt_kernel(
    const float* __restrict__ zx, const float* __restrict__ cw,
    const float* __restrict__ cb, const float* __restrict__ dt_bias,
    const float* __restrict__ A_log, float* __restrict__ out,
    float2* __restrict__ dtda, int dir)
{
    const int NCG = CONV_DIM / 4;   // 136
    int idx = blockIdx.x * 256 + threadIdx.x;
    if (idx < NTOK * NCG) {
        int cg = idx % NCG;
        int bt = idx / NCG;
        int c = cg * 4;
        int s = bt % T_LEN, b = bt / T_LEN;
        float4 acc = *(const float4*)(cb + c);
        float4 w0 = *(const float4*)(cw + (c + 0) * 4);
        float4 w1 = *(const float4*)(cw + (c + 1) * 4);
        float4 w2 = *(const float4*)(cw + (c + 2) * 4);
        float4 w3 = *(const float4*)(cw + (c + 3) * 4);
#pragma unroll
        for (int k = 0; k < D_CONV; ++k) {
            int sj = s + k - (D_CONV - 1);
            if (sj >= 0) {
                int t = dir ? (T_LEN - 1 - sj) : sj;
                float4 xv = *(const float4*)(zx + ((size_t)(b * T_LEN + t)) * D_IN_PROJ + D_INNER + c);
                acc.x += xv.x * (&w0.x)[k];
                acc.y += xv.y * (&w1.x)[k];
                acc.z += xv.z * (&w2.x)[k];
                acc.w += xv.w * (&w3.x)[k];
            }
        }
        int tout = dir ? (T_LEN - 1 - s) : s;
        float4 r = make_float4(silu_f(acc.x), silu_f(acc.y), silu_f(acc.z), silu_f(acc.w));
        *(float4*)(out + ((size_t)(b * T_LEN + tout)) * CONV_DIM + c) = r;
    } else {
        int j = idx - NTOK * NCG;
        if (j < NTOK * NHEADS) {
            int bt = j >> 3, h = j & 7;
            float dtraw = zx[(size_t)bt * D_IN_PROJ + (D_IN_PROJ - NHEADS) + h] + dt_bias[h];
            float dt = softplus_f(dtraw);
            float Ac = -expf(A_log[h]);
            dtda[(size_t)bt * NHEADS + h] = make_float2(dt, expf(dt * Ac));
        }
    }
}

// ==== chunked SSM scan v3: lane owns p, 16 n-states in registers, NO shuffles ====
__global__ __launch_bounds__(64) void scan_local_kernel(
    const float2* __restrict__ dtda, const float* __restrict__ xbc,
    const float* __restrict__ Dvec, float* __restrict__ y,
    float* __restrict__ hend, float* __restrict__ pf, int dir)
{
    __shared__ float  sx[QCH][HEADDIM];   // 8 KB
    __shared__ float  sBC[QCH][32];       // 4 KB (B | C)
    __shared__ float2 sd[QCH];            // 256 B
    int bx = blockIdx.x;                  // B*H*NCH = 2048
    int c = bx & (NCH - 1), h = (bx >> 5) & 7, b = bx >> 8;
    int p = threadIdx.x;                  // 0..63
    int s0 = c * QCH;
#pragma unroll
    for (int i = 0; i < 8; ++i) {
        int idx = i * 64 + p;
        int si = idx >> 4, l4 = (idx & 15) * 4;
        int s = s0 + si; int t = dir ? (T_LEN - 1 - s) : s;
        size_t row = (size_t)b * T_LEN + t;
        *(float4*)&sx[si][l4] = *(const float4*)(xbc + row * CONV_DIM + h * HEADDIM + l4);
    }
#pragma unroll
    for (int i = 0; i < 4; ++i) {
        int idx = i * 64 + p;
        int si = idx >> 3, l4 = (idx & 7) * 4;
        int s = s0 + si; int t = dir ? (T_LEN - 1 - s) : s;
        size_t row = (size_t)b * T_LEN + t;
        *(float4*)&sBC[si][l4] = *(const float4*)(xbc + row * CONV_DIM + D_INNER + l4);
    }
    if (p < QCH) {
        int s = s0 + p; int t = dir ? (T_LEN - 1 - s) : s;
        sd[p] = dtda[((size_t)b * T_LEN + t) * NHEADS + h];
    }
    __syncthreads();
    float Dh = Dvec[h];
    float hreg[16];
#pragma unroll
    for (int n = 0; n < 16; ++n) hreg[n] = 0.f;
    float pp = 1.f;
    for (int si = 0; si < QCH; ++si) {
        float2 dd = sd[si];
        float xv = sx[si][p];
        float dtx = dd.x * xv;
        float Bv[16], Cv[16];
#pragma unroll
        for (int j = 0; j < 4; ++j) {
            float4 t4 = *(const float4*)&sBC[si][j * 4];
            Bv[j*4+0] = t4.x; Bv[j*4+1] = t4.y; Bv[j*4+2] = t4.z; Bv[j*4+3] = t4.w;
            float4 u4 = *(const float4*)&sBC[si][16 + j * 4];
            Cv[j*4+0] = u4.x; Cv[j*4+1] = u4.y; Cv[j*4+2] = u4.z; Cv[j*4+3] = u4.w;
        }
#pragma unroll
        for (int n = 0; n < 16; ++n) hreg[n] = fmaf(hreg[n], dd.y, dtx * Bv[n]);
        float yv = Dh * xv;
#pragma unroll
        for (int n = 0; n < 16; ++n) yv = fmaf(hreg[n], Cv[n], yv);
        pp *= dd.y;
        int s = s0 + si; int t = dir ? (T_LEN - 1 - s) : s;
        y[((size_t)b * T_LEN + t) * D_INNER + h * HEADDIM + p] = yv;   // coalesced 256B
        if (p == 0) pf[((size_t)(b * NHEADS + h)) * T_LEN + s] = pp;
    }
    float4* he = (float4*)(hend + ((size_t)((b * NHEADS + h) * NCH + c)) * 1024 + p * 16);
#pragma unroll
    for (int j = 0; j < 4; ++j)
        he[j] = make_float4(hreg[j*4+0], hreg[j*4+1], hreg[j*4+2], hreg[j*4+3]);
}

// S2: prefix over chunks for 65536 independent series (elementwise in [p*16+n]).
__global__ __launch_bounds__(256) void scan_combine_kernel(
    const float* __restrict__ hend, const float* __restrict__ pf,
    float* __restrict__ hin_out)
{
    int e = blockIdx.x * 256 + threadIdx.x;   // 0..65535
    int base = e >> 10, tid = e & 1023;
    float hin = 0.f;
    for (int c = 0; c < NCH; ++c) {
        hin_out[((size_t)base * NCH + c) * 1024 + tid] = hin;
        float Pc = pf[(size_t)base * T_LEN + c * QCH + (QCH - 1)];
        hin = hend[((size_t)base * NCH + c) * 1024 + tid] + Pc * hin;
    }
}

// S3: correction y[t,p] += pf_t * sum_n hin[p][n]*C_t[n]; lane owns p, no shuffles.
__global__ __launch_bounds__(64) void scan_fix_kernel(
    const float* __restrict__ hin_in, const float* __restrict__ pf,
    const float* __restrict__ xbc, float* __restrict__ y, int dir)
{
    __shared__ float sC[QCH][16];          // 2 KB
    __shared__ float spf[QCH];             // 128 B
    int c = 1 + (blockIdx.x % (NCH - 1));
    int bh = blockIdx.x / (NCH - 1);
    int b = bh >> 3, h = bh & 7;
    int p = threadIdx.x;                   // 0..63
    size_t base = (size_t)bh;
    int s0 = c * QCH;
    float hin[16];
    {
        const float4* hp = (const float4*)(hin_in + (base * NCH + c) * 1024 + p * 16);
#pragma unroll
        for (int j = 0; j < 4; ++j) {
            float4 v = hp[j];
            hin[j*4+0] = v.x; hin[j*4+1] = v.y; hin[j*4+2] = v.z; hin[j*4+3] = v.w;
        }
    }
#pragma unroll
    for (int i = 0; i < 2; ++i) {
        int idx = i * 64 + p;
        int si = idx >> 2, l4 = (idx & 3) * 4;
        int s = s0 + si; int t = dir ? (T_LEN - 1 - s) : s;
        size_t row = (size_t)b * T_LEN + t;
        *(float4*)&sC[si][l4] = *(const float4*)(xbc + row * CONV_DIM + D_INNER + D_STATE + l4);
    }
    if (p < QCH) spf[p] = pf[base * T_LEN + s0 + p];
    __syncthreads();
    for (int si = 0; si < QCH; ++si) {
        float Cv[16];
#pragma unroll
        for (int j = 0; j < 4; ++j) {
            float4 u4 = *(const float4*)&sC[si][j * 4];
            Cv[j*4+0] = u4.x; Cv[j*4+1] = u4.y; Cv[j*4+2] = u4.z; Cv[j*4+3] = u4.w;
        }
        float yv = 0.f;
#pragma unroll
        for (int n = 0; n < 16; ++n) yv = fmaf(hin[n], Cv[n], yv);
        int s = s0 + si; int t = dir ? (T_LEN - 1 - s) : s;
        float* yp = y + ((size_t)b * T_LEN + t) * D_INNER + h * HEADDIM + p;
        *yp += spf[si] * yv;               // coalesced 256B RMW
    }
}

// ---- gated RMSNorm over 512, writes packed hi/lo ----
__global__ __launch_bounds__(512) void gated_rms_kernel(
    const float* __restrict__ y, const float* __restrict__ zx,
    const float* __restrict__ w, unsigned short* __restrict__ hi,
    unsigned short* __restrict__ lo)
{
    __shared__ float red[8];
    int row = blockIdx.x, d = threadIdx.x;
    float z = zx[(size_t)row * D_IN_PROJ + d];
    float v = y[(size_t)row * D_INNER + d] * silu_f(z);
    float ss = block_sum<8>(v * v, red);
    float r = rsqrtf(ss * (1.f / D_INNER) + EPS);
    float o = v * r * w[d];
    ushort2 s = split2(o);
    size_t off = (size_t)row * D_INNER + d;
    hi[off] = s.x; lo[off] = s.y;
}

// ---- final mean over T + logits ----
__global__ void zero_mean_kernel(float* mean) {
    int i = blockIdx.x * 256 + threadIdx.x;
    if (i < BATCH * D_MODEL) mean[i] = 0.f;
}
__global__ __launch_bounds__(256) void mean_kernel(
    const float* __restrict__ hn, float* __restrict__ mean)
{
    int b = blockIdx.x >> 4;
    int slab = blockIdx.x & 15;
    int d = threadIdx.x;
    float s = 0.f;
    int t0 = slab * 64;
    for (int t = t0; t < t0 + 64; ++t) s += hn[((size_t)(b * T_LEN + t)) * D_MODEL + d];
    atomicAdd(&mean[b * D_MODEL + d], s * (1.f / T_LEN));
}
__global__ void logits_kernel(const float* __restrict__ mean,
                              const float* __restrict__ fcw,
                              const float* __restrict__ fcb,
                              float* __restrict__ out)
{
    int tid = threadIdx.x;
    if (tid < BATCH * NCLS) {
        int b = tid / NCLS, c = tid % NCLS;
        float s = fcb[c];
        for (int d = 0; d < D_MODEL; ++d) s += mean[b * D_MODEL + d] * fcw[c * D_MODEL + d];
        out[tid] = s;
    }
}

extern "C" void kernel_launch(void* const* d_in, const int* in_sizes, int n_in,
                              void* d_out, int out_size, void* d_ws, size_t ws_size,
                              hipStream_t stream)
{
    const float* x            = (const float*)d_in[0];
    const float* input_proj_w = (const float*)d_in[1];
    const float* input_proj_b = (const float*)d_in[2];
    const float* norm1_w      = (const float*)d_in[3];
    const float* norm1_b      = (const float*)d_in[4];
    const float* in_proj_w    = (const float*)d_in[5];
    const float* conv_w       = (const float*)d_in[6];
    const float* conv_b       = (const float*)d_in[7];
    const float* dt_bias      = (const float*)d_in[8];
    const float* A_log        = (const float*)d_in[9];
    const float* Dvec         = (const float*)d_in[10];
    const float* ssm_norm_w   = (const float*)d_in[11];
    const float* out_proj_w   = (const float*)d_in[12];
    const float* norm2_w      = (const float*)d_in[13];
    const float* norm2_b      = (const float*)d_in[14];
    const float* fc1_w        = (const float*)d_in[15];
    const float* fc1_b        = (const float*)d_in[16];
    const float* fc2_w        = (const float*)d_in[17];
    const float* fc2_b        = (const float*)d_in[18];
    const float* normf_w      = (const float*)d_in[19];
    const float* normf_b      = (const float*)d_in[20];
    const float* fc_w         = (const float*)d_in[21];
    const float* fc_b         = (const float*)d_in[22];
    float* out = (float*)d_out;

    char* ws = (char*)d_ws;
    float*          RES  = (float*)(ws + 0);                 // 8 MB fp32 8192x256
    float*          H    = (float*)(ws + 8388608);           // 8 MB
    unsigned short* HNh  = (unsigned short*)(ws + 16777216); // 4 MB bf16 8192x256
    unsigned short* HNl  = (unsigned short*)(ws + 20971520); // 4 MB
    float*          ZX   = (float*)(ws + 25165824);          // 33.25 MB fp32 8192x1064
    float*          XBCC = (float*)(ws + 60030976);          // 17 MB fp32 8192x544
    float*          YSSM = (float*)(ws + 77856768);          // 16 MB fp32 8192x512
    unsigned short* YSh  = (unsigned short*)(ws + 94633984); // 8 MB bf16 8192x512
    unsigned short* YSl  = (unsigned short*)(ws + 103022592);// 8 MB
    unsigned short* GLh  = (unsigned short*)(ws + 111411200);// 4 MB bf16 8192x256
    unsigned short* GLl  = (unsigned short*)(ws + 115605504);// 4 MB
    unsigned short* WIH  = (unsigned short*)(ws + 119799808);// 2.08 MB 4x1064x256
    unsigned short* WIL  = (unsigned short*)(ws + 121978880);
    unsigned short* WOH  = (unsigned short*)(ws + 124157952);// 1 MB 4x256x512
    unsigned short* WOL  = (unsigned short*)(ws + 125206528);
    unsigned short* W1H  = (unsigned short*)(ws + 126255104);// 1 MB 4x512x256 (reordered)
    unsigned short* W1L  = (unsigned short*)(ws + 127303680);
    unsigned short* W2H  = (unsigned short*)(ws + 128352256);// 0.5 MB 4x256x256
    unsigned short* W2L  = (unsigned short*)(ws + 128876544);
    float2*         DTDA = (float2*)(ws + 129400832);        // 0.5 MB 8192x8 float2
    float*          MEAN = (float*)(ws + 129925120);         // 8 KB
    float*          HNF  = XBCC;               // alias: final LN f32 out in dead XBCC
    // scan scratch aliased into regions dead during the scan phase:
    float*          PF   = (float*)(ws + 16777216);  // 256 KB in HNh (HN dead conv..norm2)
    float*          HEND = (float*)(ws + 111411200); // 8 MB in GLh+GLl (GL dead during scan)
    float*          HIN  = (float*)(ws + 94633984);  // 8 MB in YSh (written after scan)

    // pack all layers' weights to bf16 hi/lo (once per call)
    pack_split_kernel<<<1064, 256, 0, stream>>>(in_proj_w,  WIH, WIL, NLAYERS * D_IN_PROJ * D_MODEL / 4);
    pack_split_kernel<<<512,  256, 0, stream>>>(out_proj_w, WOH, WOL, NLAYERS * D_MODEL * D_INNER / 4);
    pack_fc1_kernel  <<<512,  256, 0, stream>>>(fc1_w,      W1H, W1L, NLAYERS * 2 * D_INT * D_MODEL / 4);
    pack_split_kernel<<<256,  256, 0, stream>>>(fc2_w,      W2H, W2L, NLAYERS * D_MODEL * D_INT / 4);

    input_proj_kernel<<<NTOK, 256, 0, stream>>>(x, input_proj_w, input_proj_b, H);

    for (int i = 0; i < NLAYERS; ++i) {
        int dir = i & 1;   // odd layers: reversed-time conv+scan (flip trick)
        // residual = H (+ RES); HN = LN1(residual), packed
        add_ln_kernel<<<NTOK, 256, 0, stream>>>(
            H, i ? RES : nullptr, RES, HNh, HNl, nullptr,
            norm1_w + i * D_MODEL, norm1_b + i * D_MODEL);
        // in_proj: ZX = HN @ W^T (8192 x 1064)  -- BM=128
        {
            dim3 g((D_IN_PROJ + 63) / 64, NTOK / 128);
            gemm_mfma<128><<<g, 128, 0, stream>>>(
                HNh, HNl, WIH + (size_t)i * D_IN_PROJ * D_MODEL, WIL + (size_t)i * D_IN_PROJ * D_MODEL,
                nullptr, nullptr, ZX, D_IN_PROJ, D_MODEL);
        }
        // conv + silu + dt/dA precompute
        conv_dt_kernel<<<(NTOK * (CONV_DIM / 4) + NTOK * NHEADS + 255) / 256, 256, 0, stream>>>(
            ZX, conv_w + (size_t)i * CONV_DIM * D_CONV, conv_b + i * CONV_DIM,
            dt_bias + i * NHEADS, A_log + i * NHEADS, XBCC, DTDA, dir);
        // chunked SSM scan: local -> combine -> fix (lane-owns-p, shuffle-free)
        scan_local_kernel<<<BATCH * NHEADS * NCH, 64, 0, stream>>>(
            DTDA, XBCC, Dvec + i * NHEADS, YSSM, HEND, PF, dir);
        scan_combine_kernel<<<BATCH * NHEADS * 1024 / 256, 256, 0, stream>>>(HEND, PF, HIN);
        scan_fix_kernel<<<BATCH * NHEADS * (NCH - 1), 64, 0, stream>>>(
            HIN, PF, XBCC, YSSM, dir);
        // gated RMSNorm -> packed
        gated_rms_kernel<<<NTOK, 512, 0, stream>>>(YSSM, ZX, ssm_norm_w + i * D_INNER, YSh, YSl);
        // out_proj + residual add (RES += YS @ W^T) -- BM=64
        {
            dim3 g(D_MODEL / 64, NTOK / 64);
            gemm_mfma<64><<<g, 128, 0, stream>>>(
                YSh, YSl, WOH + (size_t)i * D_MODEL * D_INNER, WOL + (size_t)i * D_MODEL * D_INNER,
                nullptr, RES, RES, D_MODEL, D_INNER);
        }
        // norm2 -> packed
        add_ln_kernel<<<NTOK, 256, 0, stream>>>(
            RES, nullptr, nullptr, HNh, HNl, nullptr,
            norm2_w + i * D_MODEL, norm2_b + i * D_MODEL);
        // fc1 + fused GLU -> GL packed  (reordered weights; grid 8 x 128)
        {
            dim3 g((2 * D_INT) / 64, NTOK / 64);
            gemm_mfma_glu<<<g, 128, 0, stream>>>(
                HNh, HNl, W1H + (size_t)i * 2 * D_INT * D_MODEL, W1L + (size_t)i * 2 * D_INT * D_MODEL,
                fc1_b + i * 2 * D_INT, GLh, GLl, D_MODEL);
        }
        // fc2 -> H -- BM=64
        {
            dim3 g(D_MODEL / 64, NTOK / 64);
            gemm_mfma<64><<<g, 128, 0, stream>>>(
                GLh, GLl, W2H + (size_t)i * D_MODEL * D_INT, W2L + (size_t)i * D_MODEL * D_INT,
                fc2_b + i * D_MODEL, nullptr, H, D_MODEL, D_INT);
        }
    }

    // final: residual = H + RES; HNF = LNf(residual) (f32 only)
    add_ln_kernel<<<NTOK, 256, 0, stream>>>(
        H, RES, nullptr, nullptr, nullptr, HNF, normf_w, normf_b);
    zero_mean_kernel<<<(BATCH * D_MODEL + 255) / 256, 256, 0, stream>>>(MEAN);
    mean_kernel<<<BATCH * 16, 256, 0, stream>>>(HNF, MEAN);
    logits_kernel<<<1, 128, 0, stream>>>(MEAN, fc_w, fc_b, out);
}

// Round 11
// 820.830 us; speedup vs baseline: 1.7292x; 1.0559x over previous
//
#include <hip/hip_runtime.h>
#include <math.h>

#define NLAYERS   4
#define D_MODEL   256
#define D_INNER   512
#define D_STATE   16
#define NHEADS    8
#define HEADDIM   64
#define D_CONV    4
#define D_INT     256
#define NCLS      10
#define IN_FEAT   64
#define T_LEN     1024
#define BATCH     8
#define D_IN_PROJ 1064   // 2*512 + 2*16 + 8
#define CONV_DIM  544    // 512 + 32
#define EPS       1e-5f
#define NTOK      (BATCH*T_LEN)   // 8192
#define QCH       32             // scan chunk length
#define NCH       (T_LEN/QCH)    // 32 chunks

typedef __attribute__((ext_vector_type(8))) short bf16x8;
typedef __attribute__((ext_vector_type(4))) float f32x4;

__device__ __forceinline__ float silu_f(float x) { return x / (1.f + expf(-x)); }
__device__ __forceinline__ float softplus_f(float x) { return x > 20.f ? x : log1pf(expf(x)); }

// ---- async global->LDS 16B DMA (dest must be wave-uniform base + lane*16) ----
typedef __attribute__((address_space(3))) void       lds_void_t;
typedef __attribute__((address_space(1))) const void gbl_void_t;
__device__ __forceinline__ void gload16(void* lds, const void* g) {
    __builtin_amdgcn_global_load_lds((gbl_void_t*)g, (lds_void_t*)lds, 16, 0, 0);
}

// ---- fp32 -> bf16 (RNE) split helpers ----
__device__ __forceinline__ unsigned short f2bf(float f) {
    unsigned u = __float_as_uint(f);
    return (unsigned short)((u + 0x7fffu + ((u >> 16) & 1u)) >> 16);
}
__device__ __forceinline__ float bf2f(unsigned short h) {
    return __uint_as_float((unsigned)h << 16);
}
__device__ __forceinline__ ushort2 split2(float f) {
    unsigned short hi = f2bf(f);
    unsigned short lo = f2bf(f - bf2f(hi));
    return make_ushort2(hi, lo);
}

// ---- block reduction: NW waves of 64 lanes ----
template<int NW>
__device__ __forceinline__ float block_sum(float v, float* red) {
#pragma unroll
    for (int off = 32; off > 0; off >>= 1) v += __shfl_down(v, off, 64);
    int lane = threadIdx.x & 63, wid = threadIdx.x >> 6;
    __syncthreads();
    if (lane == 0) red[wid] = v;
    __syncthreads();
    float s = 0.f;
#pragma unroll
    for (int i = 0; i < NW; ++i) s += red[i];
    return s;
}

// ---- weight pack: fp32 -> (hi,lo) bf16, vectorized ----
__global__ __launch_bounds__(256) void pack_split_kernel(
    const float* __restrict__ src, unsigned short* __restrict__ hi,
    unsigned short* __restrict__ lo, int n4)
{
    int i = blockIdx.x * 256 + threadIdx.x;
    if (i >= n4) return;
    float4 v = ((const float4*)src)[i];
    ushort2 a = split2(v.x), b = split2(v.y), c = split2(v.z), d = split2(v.w);
    ((ushort4*)hi)[i] = make_ushort4(a.x, b.x, c.x, d.x);
    ((ushort4*)lo)[i] = make_ushort4(a.y, b.y, c.y, d.y);
}

// ---- fc1 pack with row reorder for fused GLU:
// new row r (in [0,512) per layer): x=r/64, i=r%64;
// orig = i<32 ? x*32+i  (y1 col)  :  256 + x*32 + (i-32)  (gate col)
__global__ __launch_bounds__(256) void pack_fc1_kernel(
    const float* __restrict__ src, unsigned short* __restrict__ hi,
    unsigned short* __restrict__ lo, int n4)
{
    int i4 = blockIdx.x * 256 + threadIdx.x;
    if (i4 >= n4) return;
    int gl  = i4 / (512 * 64);          // layer
    int rem = i4 % (512 * 64);
    int r   = rem / 64;                 // reordered row
    int k4  = rem % 64;                 // float4 index in row (K=256)
    int x = r >> 6, ii = r & 63;
    int orig = (ii < 32) ? (x * 32 + ii) : (256 + x * 32 + (ii - 32));
    float4 v = ((const float4*)src)[(gl * 512 + orig) * 64 + k4];
    ushort2 a = split2(v.x), b = split2(v.y), c = split2(v.z), d = split2(v.w);
    ((ushort4*)hi)[i4] = make_ushort4(a.x, b.x, c.x, d.x);
    ((ushort4*)lo)[i4] = make_ushort4(a.y, b.y, c.y, d.y);
}

// ---- input projection v2: 16 tokens/block, weight row in regs (16x reuse) ----
#define TT 16
__global__ __launch_bounds__(256) void input_proj_kernel(
    const float* __restrict__ x, const float* __restrict__ w,
    const float* __restrict__ bias, float* __restrict__ h)
{
    __shared__ float xs[TT][IN_FEAT + 4];   // 68 floats/row: rows 16B-aligned, banks spread
    int blk = blockIdx.x;                   // 512 blocks
    int b = blk / (T_LEN / TT), tc = blk % (T_LEN / TT);
    int t0 = tc * TT;
    int tid = threadIdx.x;
    // stage transposed: x[b, f, t0..t0+16) -> xs[t][f]; coalesced float4 along t
    {
        int f = tid >> 2, j = tid & 3;
        float4 v = *(const float4*)(x + ((size_t)(b * IN_FEAT + f)) * T_LEN + t0 + j * 4);
        xs[j * 4 + 0][f] = v.x;
        xs[j * 4 + 1][f] = v.y;
        xs[j * 4 + 2][f] = v.z;
        xs[j * 4 + 3][f] = v.w;
    }
    __syncthreads();
    int d = tid;
    float4 wr[16];
    const float4* wp = (const float4*)(w + d * IN_FEAT);
#pragma unroll
    for (int i = 0; i < 16; ++i) wr[i] = wp[i];
    float bv = bias[d];
#pragma unroll
    for (int t = 0; t < TT; ++t) {
        float acc = bv;
#pragma unroll
        for (int i = 0; i < 16; ++i) {
            float4 xv = *(const float4*)&xs[t][i * 4];
            acc += xv.x * wr[i].x + xv.y * wr[i].y + xv.z * wr[i].z + xv.w * wr[i].w;
        }
        h[((size_t)(b * T_LEN + t0 + t)) * D_MODEL + d] = acc;   // coalesced
    }
}

// ---- fused (optional add) + LayerNorm over 256, writes packed hi/lo and/or f32 ----
__global__ __launch_bounds__(256) void add_ln_kernel(
    const float* __restrict__ a, const float* __restrict__ b,
    float* __restrict__ sum_out, unsigned short* __restrict__ hi,
    unsigned short* __restrict__ lo, float* __restrict__ f32out,
    const float* __restrict__ w, const float* __restrict__ bias)
{
    __shared__ float red[4];
    int row = blockIdx.x, d = threadIdx.x;
    size_t o = (size_t)row * D_MODEL + d;
    float v = a[o];
    if (b) v += b[o];
    if (sum_out) sum_out[o] = v;
    float mean = block_sum<4>(v, red) * (1.f / D_MODEL);
    float xc = v - mean;
    float var = block_sum<4>(xc * xc, red) * (1.f / D_MODEL);
    float r = xc * rsqrtf(var + EPS) * w[d] + bias[d];
    if (hi) { ushort2 s = split2(r); hi[o] = s.x; lo[o] = s.y; }
    if (f32out) f32out[o] = r;
}

// ---- MFMA GEMM: C = A@W^T (+bias)(+resid)
// LDS k-chunk XOR swizzle (both-sides: pre-swizzled GLOBAL source + swizzled read;
// LDS dest stays linear per global_load_lds constraint). Read banks: 8-way -> 2-way.
template<int BM>
__global__ __launch_bounds__(128) void gemm_mfma(
    const unsigned short* __restrict__ Ahi, const unsigned short* __restrict__ Alo,
    const unsigned short* __restrict__ Whi, const unsigned short* __restrict__ Wlo,
    const float* __restrict__ bias, const float* __restrict__ resid,
    float* __restrict__ C, int N, int K)
{
    constexpr int MFRAG   = BM / 32;
    constexpr int AROUNDS = BM / 32;
    __shared__ unsigned short sAh[BM * 32], sAl[BM * 32];
    __shared__ unsigned short sBh[64 * 32], sBl[64 * 32];
    const int tid = threadIdx.x;
    const int lane = tid & 63, wm = tid >> 6;
    const int m0 = blockIdx.y * BM, n0 = blockIdx.x * 64;

    const int srow = tid >> 2;
    const int sk   = (((tid & 3) ^ ((srow >> 1) & 3)) * 8);   // swizzled k-chunk source
    const unsigned short* gAh = Ahi + (size_t)(m0 + srow) * K + sk;
    const unsigned short* gAl = Alo + (size_t)(m0 + srow) * K + sk;
    int bn  = n0 + srow;      if (bn  > N - 1) bn  = N - 1;
    int bn2 = n0 + 32 + srow; if (bn2 > N - 1) bn2 = N - 1;
    const unsigned short* gBh  = Whi + (size_t)bn  * K + sk;
    const unsigned short* gBh2 = Whi + (size_t)bn2 * K + sk;
    const unsigned short* gBl  = Wlo + (size_t)bn  * K + sk;
    const unsigned short* gBl2 = Wlo + (size_t)bn2 * K + sk;
    const size_t rK32 = (size_t)32 * K;

    const int fr = lane & 15, kg = lane >> 4;
    const int kgs = kg ^ ((fr >> 1) & 3);                      // swizzled read chunk
    const int abase = (wm * (BM / 2) + fr) * 32 + kgs * 8;
    const int bbase = fr * 32 + kgs * 8;

    f32x4 acc[MFRAG][4] = {};

    for (int k0 = 0; k0 < K; k0 += 32) {
#pragma unroll
        for (int rr = 0; rr < AROUNDS; ++rr) {
            gload16(&sAh[tid * 8 + rr * 1024], gAh + (size_t)rr * rK32);
            gload16(&sAl[tid * 8 + rr * 1024], gAl + (size_t)rr * rK32);
        }
        gload16(&sBh[tid * 8],        gBh);
        gload16(&sBh[tid * 8 + 1024], gBh2);
        gload16(&sBl[tid * 8],        gBl);
        gload16(&sBl[tid * 8 + 1024], gBl2);
        gAh += 32; gAl += 32; gBh += 32; gBh2 += 32; gBl += 32; gBl2 += 32;
        __syncthreads();

        bf16x8 ah[MFRAG], al[MFRAG], bh[4], bl[4];
#pragma unroll
        for (int fm = 0; fm < MFRAG; ++fm) {
            ah[fm] = *(const bf16x8*)&sAh[abase + fm * 512];
            al[fm] = *(const bf16x8*)&sAl[abase + fm * 512];
        }
#pragma unroll
        for (int fn = 0; fn < 4; ++fn) {
            bh[fn] = *(const bf16x8*)&sBh[bbase + fn * 512];
            bl[fn] = *(const bf16x8*)&sBl[bbase + fn * 512];
        }
#pragma unroll
        for (int fm = 0; fm < MFRAG; ++fm)
#pragma unroll
            for (int fn = 0; fn < 4; ++fn) {
                acc[fm][fn] = __builtin_amdgcn_mfma_f32_16x16x32_bf16(ah[fm], bh[fn], acc[fm][fn], 0, 0, 0);
                acc[fm][fn] = __builtin_amdgcn_mfma_f32_16x16x32_bf16(ah[fm], bl[fn], acc[fm][fn], 0, 0, 0);
                acc[fm][fn] = __builtin_amdgcn_mfma_f32_16x16x32_bf16(al[fm], bh[fn], acc[fm][fn], 0, 0, 0);
            }
        __syncthreads();
    }

    const int orow0 = kg * 4;
#pragma unroll
    for (int fm = 0; fm < MFRAG; ++fm)
#pragma unroll
        for (int fn = 0; fn < 4; ++fn) {
            int n = n0 + fn * 16 + fr;
            if (n < N) {
                float bv = bias ? bias[n] : 0.f;
#pragma unroll
                for (int r = 0; r < 4; ++r) {
                    int m = m0 + wm * (BM / 2) + fm * 16 + orow0 + r;
                    size_t off = (size_t)m * N + n;
                    float v = acc[fm][fn][r] + bv;
                    if (resid) v += resid[off];
                    C[off] = v;
                }
            }
        }
}

// ---- fc1 GEMM with fused GLU epilogue (weights pre-reordered by pack_fc1).
__global__ __launch_bounds__(128) void gemm_mfma_glu(
    const unsigned short* __restrict__ Ahi, const unsigned short* __restrict__ Alo,
    const unsigned short* __restrict__ Whi, const unsigned short* __restrict__ Wlo,
    const float* __restrict__ bias,   // original fc1_b (512 per layer)
    unsigned short* __restrict__ Ghi, unsigned short* __restrict__ Glo, int K)
{
    constexpr int BM = 64;
    __shared__ unsigned short sAh[BM * 32], sAl[BM * 32];
    __shared__ unsigned short sBh[64 * 32], sBl[64 * 32];
    const int tid = threadIdx.x;
    const int lane = tid & 63, wm = tid >> 6;
    const int m0 = blockIdx.y * BM, n0 = blockIdx.x * 64;

    const int srow = tid >> 2;
    const int sk   = (((tid & 3) ^ ((srow >> 1) & 3)) * 8);
    const unsigned short* gAh = Ahi + (size_t)(m0 + srow) * K + sk;
    const unsigned short* gAl = Alo + (size_t)(m0 + srow) * K + sk;
    const unsigned short* gBh  = Whi + (size_t)(n0 + srow) * K + sk;
    const unsigned short* gBh2 = Whi + (size_t)(n0 + 32 + srow) * K + sk;
    const unsigned short* gBl  = Wlo + (size_t)(n0 + srow) * K + sk;
    const unsigned short* gBl2 = Wlo + (size_t)(n0 + 32 + srow) * K + sk;
    const size_t rK32 = (size_t)32 * K;

    const int fr = lane & 15, kg = lane >> 4;
    const int kgs = kg ^ ((fr >> 1) & 3);
    const int abase = (wm * 32 + fr) * 32 + kgs * 8;
    const int bbase = fr * 32 + kgs * 8;

    f32x4 acc[2][4] = {};

    for (int k0 = 0; k0 < K; k0 += 32) {
#pragma unroll
        for (int rr = 0; rr < 2; ++rr) {
            gload16(&sAh[tid * 8 + rr * 1024], gAh + (size_t)rr * rK32);
            gload16(&sAl[tid * 8 + rr * 1024], gAl + (size_t)rr * rK32);
        }
        gload16(&sBh[tid * 8],        gBh);
        gload16(&sBh[tid * 8 + 1024], gBh2);
        gload16(&sBl[tid * 8],        gBl);
        gload16(&sBl[tid * 8 + 1024], gBl2);
        gAh += 32; gAl += 32; gBh += 32; gBh2 += 32; gBl += 32; gBl2 += 32;
        __syncthreads();

        bf16x8 ah[2], al[2], bh[4], bl[4];
#pragma unroll
        for (int fm = 0; fm < 2; ++fm) {
            ah[fm] = *(const bf16x8*)&sAh[abase + fm * 512];
            al[fm] = *(const bf16x8*)&sAl[abase + fm * 512];
        }
#pragma unroll
        for (int fn = 0; fn < 4; ++fn) {
            bh[fn] = *(const bf16x8*)&sBh[bbase + fn * 512];
            bl[fn] = *(const bf16x8*)&sBl[bbase + fn * 512];
        }
#pragma unroll
        for (int fm = 0; fm < 2; ++fm)
#pragma unroll
            for (int fn = 0; fn < 4; ++fn) {
                acc[fm][fn] = __builtin_amdgcn_mfma_f32_16x16x32_bf16(ah[fm], bh[fn], acc[fm][fn], 0, 0, 0);
                acc[fm][fn] = __builtin_amdgcn_mfma_f32_16x16x32_bf16(ah[fm], bl[fn], acc[fm][fn], 0, 0, 0);
                acc[fm][fn] = __builtin_amdgcn_mfma_f32_16x16x32_bf16(al[fm], bh[fn], acc[fm][fn], 0, 0, 0);
            }
        __syncthreads();
    }

    // fused GLU epilogue
    const int orow0 = kg * 4;
#pragma unroll
    for (int fm = 0; fm < 2; ++fm)
#pragma unroll
        for (int fn = 0; fn < 2; ++fn) {
            int lc = (n0 >> 1) + fn * 16 + fr;        // logical GL col 0..255
            float by = bias[lc], bg = bias[256 + lc];
#pragma unroll
            for (int r = 0; r < 4; ++r) {
                int m = m0 + wm * 32 + fm * 16 + orow0 + r;
                float y1 = acc[fm][fn][r] + by;
                float gt = acc[fm][fn + 2][r] + bg;
                float g  = y1 * silu_f(gt);
                ushort2 s = split2(g);
                size_t off = (size_t)m * D_INT + lc;
                Ghi[off] = s.x; Glo[off] = s.y;
            }
        }
}

// ---- depthwise causal conv (K=4) + silu (float4 over channels), fused dt/dA ----
__global__ __launch_bounds__(256) void conv_dt_kernel(
    const float* __restrict__ zx, const float* __restrict__ cw,
    const float* __restrict__ cb, const float* __restrict__ dt_bias,
    const float* __restrict__ A_log, float* __restrict__ out,
    float2* __restrict__ dtda, int dir)
{
    const int NCG = CONV_DIM / 4;   // 136
    int idx = blockIdx.x * 256 + threadIdx.x;
    if (idx < NTOK * NCG) {
        int cg = idx % NCG;
        int bt = idx / NCG;
        int c = cg * 4;
        int s = bt % T_LEN, b = bt / T_LEN;
        float4 acc = *(const float4*)(cb + c);
        float4 w0 = *(const float4*)(cw + (c + 0) * 4);
        float4 w1 = *(const float4*)(cw + (c + 1) * 4);
        float4 w2 = *(const float4*)(cw + (c + 2) * 4);
        float4 w3 = *(const float4*)(cw + (c + 3) * 4);
#pragma unroll
        for (int k = 0; k < D_CONV; ++k) {
            int sj = s + k - (D_CONV - 1);
            if (sj >= 0) {
                int t = dir ? (T_LEN - 1 - sj) : sj;
                float4 xv = *(const float4*)(zx + ((size_t)(b * T_LEN + t)) * D_IN_PROJ + D_INNER + c);
                acc.x += xv.x * (&w0.x)[k];
                acc.y += xv.y * (&w1.x)[k];
                acc.z += xv.z * (&w2.x)[k];
                acc.w += xv.w * (&w3.x)[k];
            }
        }
        int tout = dir ? (T_LEN - 1 - s) : s;
        float4 r = make_float4(silu_f(acc.x), silu_f(acc.y), silu_f(acc.z), silu_f(acc.w));
        *(float4*)(out + ((size_t)(b * T_LEN + tout)) * CONV_DIM + c) = r;
    } else {
        int j = idx - NTOK * NCG;
        if (j < NTOK * NHEADS) {
            int bt = j >> 3, h = j & 7;
            float dtraw = zx[(size_t)bt * D_IN_PROJ + (D_IN_PROJ - NHEADS) + h] + dt_bias[h];
            float dt = softplus_f(dtraw);
            float Ac = -expf(A_log[h]);
            dtda[(size_t)bt * NHEADS + h] = make_float2(dt, expf(dt * Ac));
        }
    }
}

// ==== chunked SSM scan v3: lane owns p, 16 n-states in registers, NO shuffles ====
__global__ __launch_bounds__(64) void scan_local_kernel(
    const float2* __restrict__ dtda, const float* __restrict__ xbc,
    const float* __restrict__ Dvec, float* __restrict__ y,
    float* __restrict__ hend, float* __restrict__ pf, int dir)
{
    __shared__ float  sx[QCH][HEADDIM];   // 8 KB
    __shared__ float  sBC[QCH][32];       // 4 KB (B | C)
    __shared__ float2 sd[QCH];            // 256 B
    int bx = blockIdx.x;                  // B*H*NCH = 2048
    int c = bx & (NCH - 1), h = (bx >> 5) & 7, b = bx >> 8;
    int p = threadIdx.x;                  // 0..63
    int s0 = c * QCH;
#pragma unroll
    for (int i = 0; i < 8; ++i) {
        int idx = i * 64 + p;
        int si = idx >> 4, l4 = (idx & 15) * 4;
        int s = s0 + si; int t = dir ? (T_LEN - 1 - s) : s;
        size_t row = (size_t)b * T_LEN + t;
        *(float4*)&sx[si][l4] = *(const float4*)(xbc + row * CONV_DIM + h * HEADDIM + l4);
    }
#pragma unroll
    for (int i = 0; i < 4; ++i) {
        int idx = i * 64 + p;
        int si = idx >> 3, l4 = (idx & 7) * 4;
        int s = s0 + si; int t = dir ? (T_LEN - 1 - s) : s;
        size_t row = (size_t)b * T_LEN + t;
        *(float4*)&sBC[si][l4] = *(const float4*)(xbc + row * CONV_DIM + D_INNER + l4);
    }
    if (p < QCH) {
        int s = s0 + p; int t = dir ? (T_LEN - 1 - s) : s;
        sd[p] = dtda[((size_t)b * T_LEN + t) * NHEADS + h];
    }
    __syncthreads();
    float Dh = Dvec[h];
    float hreg[16];
#pragma unroll
    for (int n = 0; n < 16; ++n) hreg[n] = 0.f;
    float pp = 1.f;
    for (int si = 0; si < QCH; ++si) {
        float2 dd = sd[si];
        float xv = sx[si][p];
        float dtx = dd.x * xv;
        float Bv[16], Cv[16];
#pragma unroll
        for (int j = 0; j < 4; ++j) {
            float4 t4 = *(const float4*)&sBC[si][j * 4];
            Bv[j*4+0] = t4.x; Bv[j*4+1] = t4.y; Bv[j*4+2] = t4.z; Bv[j*4+3] = t4.w;
            float4 u4 = *(const float4*)&sBC[si][16 + j * 4];
            Cv[j*4+0] = u4.x; Cv[j*4+1] = u4.y; Cv[j*4+2] = u4.z; Cv[j*4+3] = u4.w;
        }
#pragma unroll
        for (int n = 0; n < 16; ++n) hreg[n] = fmaf(hreg[n], dd.y, dtx * Bv[n]);
        float yv = Dh * xv;
#pragma unroll
        for (int n = 0; n < 16; ++n) yv = fmaf(hreg[n], Cv[n], yv);
        pp *= dd.y;
        int s = s0 + si; int t = dir ? (T_LEN - 1 - s) : s;
        y[((size_t)b * T_LEN + t) * D_INNER + h * HEADDIM + p] = yv;   // coalesced 256B
        if (p == 0) pf[((size_t)(b * NHEADS + h)) * T_LEN + s] = pp;
    }
    float4* he = (float4*)(hend + ((size_t)((b * NHEADS + h) * NCH + c)) * 1024 + p * 16);
#pragma unroll
    for (int j = 0; j < 4; ++j)
        he[j] = make_float4(hreg[j*4+0], hreg[j*4+1], hreg[j*4+2], hreg[j*4+3]);
}

// S2: prefix over chunks for 65536 independent series (elementwise in [p*16+n]).
__global__ __launch_bounds__(256) void scan_combine_kernel(
    const float* __restrict__ hend, const float* __restrict__ pf,
    float* __restrict__ hin_out)
{
    int e = blockIdx.x * 256 + threadIdx.x;   // 0..65535
    int base = e >> 10, tid = e & 1023;
    float hin = 0.f;
    for (int c = 0; c < NCH; ++c) {
        hin_out[((size_t)base * NCH + c) * 1024 + tid] = hin;
        float Pc = pf[(size_t)base * T_LEN + c * QCH + (QCH - 1)];
        hin = hend[((size_t)base * NCH + c) * 1024 + tid] + Pc * hin;
    }
}

// S3: correction y[t,p] += pf_t * sum_n hin[p][n]*C_t[n]; lane owns p, no shuffles.
__global__ __launch_bounds__(64) void scan_fix_kernel(
    const float* __restrict__ hin_in, const float* __restrict__ pf,
    const float* __restrict__ xbc, float* __restrict__ y, int dir)
{
    __shared__ float sC[QCH][16];          // 2 KB
    __shared__ float spf[QCH];             // 128 B
    int c = 1 + (blockIdx.x % (NCH - 1));
    int bh = blockIdx.x / (NCH - 1);
    int b = bh >> 3, h = bh & 7;
    int p = threadIdx.x;                   // 0..63
    size_t base = (size_t)bh;
    int s0 = c * QCH;
    float hin[16];
    {
        const float4* hp = (const float4*)(hin_in + (base * NCH + c) * 1024 + p * 16);
#pragma unroll
        for (int j = 0; j < 4; ++j) {
            float4 v = hp[j];
            hin[j*4+0] = v.x; hin[j*4+1] = v.y; hin[j*4+2] = v.z; hin[j*4+3] = v.w;
        }
    }
#pragma unroll
    for (int i = 0; i < 2; ++i) {
        int idx = i * 64 + p;
        int si = idx >> 2, l4 = (idx & 3) * 4;
        int s = s0 + si; int t = dir ? (T_LEN - 1 - s) : s;
        size_t row = (size_t)b * T_LEN + t;
        *(float4*)&sC[si][l4] = *(const float4*)(xbc + row * CONV_DIM + D_INNER + D_STATE + l4);
    }
    if (p < QCH) spf[p] = pf[base * T_LEN + s0 + p];
    __syncthreads();
    for (int si = 0; si < QCH; ++si) {
        float Cv[16];
#pragma unroll
        for (int j = 0; j < 4; ++j) {
            float4 u4 = *(const float4*)&sC[si][j * 4];
            Cv[j*4+0] = u4.x; Cv[j*4+1] = u4.y; Cv[j*4+2] = u4.z; Cv[j*4+3] = u4.w;
        }
        float yv = 0.f;
#pragma unroll
        for (int n = 0; n < 16; ++n) yv = fmaf(hin[n], Cv[n], yv);
        int s = s0 + si; int t = dir ? (T_LEN - 1 - s) : s;
        float* yp = y + ((size_t)b * T_LEN + t) * D_INNER + h * HEADDIM + p;
        *yp += spf[si] * yv;               // coalesced 256B RMW
    }
}

// ---- gated RMSNorm over 512, writes packed hi/lo ----
__global__ __launch_bounds__(512) void gated_rms_kernel(
    const float* __restrict__ y, const float* __restrict__ zx,
    const float* __restrict__ w, unsigned short* __restrict__ hi,
    unsigned short* __restrict__ lo)
{
    __shared__ float red[8];
    int row = blockIdx.x, d = threadIdx.x;
    float z = zx[(size_t)row * D_IN_PROJ + d];
    float v = y[(size_t)row * D_INNER + d] * silu_f(z);
    float ss = block_sum<8>(v * v, red);
    float r = rsqrtf(ss * (1.f / D_INNER) + EPS);
    float o = v * r * w[d];
    ushort2 s = split2(o);
    size_t off = (size_t)row * D_INNER + d;
    hi[off] = s.x; lo[off] = s.y;
}

// ---- final mean over T + logits ----
__global__ void zero_mean_kernel(float* mean) {
    int i = blockIdx.x * 256 + threadIdx.x;
    if (i < BATCH * D_MODEL) mean[i] = 0.f;
}
__global__ __launch_bounds__(256) void mean_kernel(
    const float* __restrict__ hn, float* __restrict__ mean)
{
    int b = blockIdx.x >> 4;
    int slab = blockIdx.x & 15;
    int d = threadIdx.x;
    float s = 0.f;
    int t0 = slab * 64;
    for (int t = t0; t < t0 + 64; ++t) s += hn[((size_t)(b * T_LEN + t)) * D_MODEL + d];
    atomicAdd(&mean[b * D_MODEL + d], s * (1.f / T_LEN));
}
__global__ void logits_kernel(const float* __restrict__ mean,
                              const float* __restrict__ fcw,
                              const float* __restrict__ fcb,
                              float* __restrict__ out)
{
    int tid = threadIdx.x;
    if (tid < BATCH * NCLS) {
        int b = tid / NCLS, c = tid % NCLS;
        float s = fcb[c];
        for (int d = 0; d < D_MODEL; ++d) s += mean[b * D_MODEL + d] * fcw[c * D_MODEL + d];
        out[tid] = s;
    }
}

extern "C" void kernel_launch(void* const* d_in, const int* in_sizes, int n_in,
                              void* d_out, int out_size, void* d_ws, size_t ws_size,
                              hipStream_t stream)
{
    const float* x            = (const float*)d_in[0];
    const float* input_proj_w = (const float*)d_in[1];
    const float* input_proj_b = (const float*)d_in[2];
    const float* norm1_w      = (const float*)d_in[3];
    const float* norm1_b      = (const float*)d_in[4];
    const float* in_proj_w    = (const float*)d_in[5];
    const float* conv_w       = (const float*)d_in[6];
    const float* conv_b       = (const float*)d_in[7];
    const float* dt_bias      = (const float*)d_in[8];
    const float* A_log        = (const float*)d_in[9];
    const float* Dvec         = (const float*)d_in[10];
    const float* ssm_norm_w   = (const float*)d_in[11];
    const float* out_proj_w   = (const float*)d_in[12];
    const float* norm2_w      = (const float*)d_in[13];
    const float* norm2_b      = (const float*)d_in[14];
    const float* fc1_w        = (const float*)d_in[15];
    const float* fc1_b        = (const float*)d_in[16];
    const float* fc2_w        = (const float*)d_in[17];
    const float* fc2_b        = (const float*)d_in[18];
    const float* normf_w      = (const float*)d_in[19];
    const float* normf_b      = (const float*)d_in[20];
    const float* fc_w         = (const float*)d_in[21];
    const float* fc_b         = (const float*)d_in[22];
    float* out = (float*)d_out;

    char* ws = (char*)d_ws;
    float*          RES  = (float*)(ws + 0);                 // 8 MB fp32 8192x256
    float*          H    = (float*)(ws + 8388608);           // 8 MB
    unsigned short* HNh  = (unsigned short*)(ws + 16777216); // 4 MB bf16 8192x256
    unsigned short* HNl  = (unsigned short*)(ws + 20971520); // 4 MB
    float*          ZX   = (float*)(ws + 25165824);          // 33.25 MB fp32 8192x1064
    float*          XBCC = (float*)(ws + 60030976);          // 17 MB fp32 8192x544
    float*          YSSM = (float*)(ws + 77856768);          // 16 MB fp32 8192x512
    unsigned short* YSh  = (unsigned short*)(ws + 94633984); // 8 MB bf16 8192x512
    unsigned short* YSl  = (unsigned short*)(ws + 103022592);// 8 MB
    unsigned short* GLh  = (unsigned short*)(ws + 111411200);// 4 MB bf16 8192x256
    unsigned short* GLl  = (unsigned short*)(ws + 115605504);// 4 MB
    unsigned short* WIH  = (unsigned short*)(ws + 119799808);// 2.08 MB 4x1064x256
    unsigned short* WIL  = (unsigned short*)(ws + 121978880);
    unsigned short* WOH  = (unsigned short*)(ws + 124157952);// 1 MB 4x256x512
    unsigned short* WOL  = (unsigned short*)(ws + 125206528);
    unsigned short* W1H  = (unsigned short*)(ws + 126255104);// 1 MB 4x512x256 (reordered)
    unsigned short* W1L  = (unsigned short*)(ws + 127303680);
    unsigned short* W2H  = (unsigned short*)(ws + 128352256);// 0.5 MB 4x256x256
    unsigned short* W2L  = (unsigned short*)(ws + 128876544);
    float2*         DTDA = (float2*)(ws + 129400832);        // 0.5 MB 8192x8 float2
    float*          MEAN = (float*)(ws + 129925120);         // 8 KB
    float*          HNF  = XBCC;               // alias: final LN f32 out in dead XBCC
    // scan scratch aliased into regions dead during the scan phase:
    float*          PF   = (float*)(ws + 16777216);  // 256 KB in HNh (HN dead conv..norm2)
    float*          HEND = (float*)(ws + 111411200); // 8 MB in GLh+GLl (GL dead during scan)
    float*          HIN  = (float*)(ws + 94633984);  // 8 MB in YSh (written after scan)

    // pack all layers' weights to bf16 hi/lo (once per call)
    pack_split_kernel<<<1064, 256, 0, stream>>>(in_proj_w,  WIH, WIL, NLAYERS * D_IN_PROJ * D_MODEL / 4);
    pack_split_kernel<<<512,  256, 0, stream>>>(out_proj_w, WOH, WOL, NLAYERS * D_MODEL * D_INNER / 4);
    pack_fc1_kernel  <<<512,  256, 0, stream>>>(fc1_w,      W1H, W1L, NLAYERS * 2 * D_INT * D_MODEL / 4);
    pack_split_kernel<<<256,  256, 0, stream>>>(fc2_w,      W2H, W2L, NLAYERS * D_MODEL * D_INT / 4);

    input_proj_kernel<<<BATCH * (T_LEN / TT), 256, 0, stream>>>(x, input_proj_w, input_proj_b, H);

    for (int i = 0; i < NLAYERS; ++i) {
        int dir = i & 1;   // odd layers: reversed-time conv+scan (flip trick)
        // residual = H (+ RES); HN = LN1(residual), packed
        add_ln_kernel<<<NTOK, 256, 0, stream>>>(
            H, i ? RES : nullptr, RES, HNh, HNl, nullptr,
            norm1_w + i * D_MODEL, norm1_b + i * D_MODEL);
        // in_proj: ZX = HN @ W^T (8192 x 1064)  -- BM=128
        {
            dim3 g((D_IN_PROJ + 63) / 64, NTOK / 128);
            gemm_mfma<128><<<g, 128, 0, stream>>>(
                HNh, HNl, WIH + (size_t)i * D_IN_PROJ * D_MODEL, WIL + (size_t)i * D_IN_PROJ * D_MODEL,
                nullptr, nullptr, ZX, D_IN_PROJ, D_MODEL);
        }
        // conv + silu + dt/dA precompute
        conv_dt_kernel<<<(NTOK * (CONV_DIM / 4) + NTOK * NHEADS + 255) / 256, 256, 0, stream>>>(
            ZX, conv_w + (size_t)i * CONV_DIM * D_CONV, conv_b + i * CONV_DIM,
            dt_bias + i * NHEADS, A_log + i * NHEADS, XBCC, DTDA, dir);
        // chunked SSM scan: local -> combine -> fix (lane-owns-p, shuffle-free)
        scan_local_kernel<<<BATCH * NHEADS * NCH, 64, 0, stream>>>(
            DTDA, XBCC, Dvec + i * NHEADS, YSSM, HEND, PF, dir);
        scan_combine_kernel<<<BATCH * NHEADS * 1024 / 256, 256, 0, stream>>>(HEND, PF, HIN);
        scan_fix_kernel<<<BATCH * NHEADS * (NCH - 1), 64, 0, stream>>>(
            HIN, PF, XBCC, YSSM, dir);
        // gated RMSNorm -> packed
        gated_rms_kernel<<<NTOK, 512, 0, stream>>>(YSSM, ZX, ssm_norm_w + i * D_INNER, YSh, YSl);
        // out_proj + residual add (RES += YS @ W^T) -- BM=64
        {
            dim3 g(D_MODEL / 64, NTOK / 64);
            gemm_mfma<64><<<g, 128, 0, stream>>>(
                YSh, YSl, WOH + (size_t)i * D_MODEL * D_INNER, WOL + (size_t)i * D_MODEL * D_INNER,
                nullptr, RES, RES, D_MODEL, D_INNER);
        }
        // norm2 -> packed
        add_ln_kernel<<<NTOK, 256, 0, stream>>>(
            RES, nullptr, nullptr, HNh, HNl, nullptr,
            norm2_w + i * D_MODEL, norm2_b + i * D_MODEL);
        // fc1 + fused GLU -> GL packed  (reordered weights; grid 8 x 128)
        {
            dim3 g((2 * D_INT) / 64, NTOK / 64);
            gemm_mfma_glu<<<g, 128, 0, stream>>>(
                HNh, HNl, W1H + (size_t)i * 2 * D_INT * D_MODEL, W1L + (size_t)i * 2 * D_INT * D_MODEL,
                fc1_b + i * 2 * D_INT, GLh, GLl, D_MODEL);
        }
        // fc2 -> H -- BM=64
        {
            dim3 g(D_MODEL / 64, NTOK / 64);
            gemm_mfma<64><<<g, 128, 0, stream>>>(
                GLh, GLl, W2H + (size_t)i * D_MODEL * D_INT, W2L + (size_t)i * D_MODEL * D_INT,
                fc2_b + i * D_MODEL, nullptr, H, D_MODEL, D_INT);
        }
    }

    // final: residual = H + RES; HNF = LNf(residual) (f32 only)
    add_ln_kernel<<<NTOK, 256, 0, stream>>>(
        H, RES, nullptr, nullptr, nullptr, HNF, normf_w, normf_b);
    zero_mean_kernel<<<(BATCH * D_MODEL + 255) / 256, 256, 0, stream>>>(MEAN);
    mean_kernel<<<BATCH * 16, 256, 0, stream>>>(HNF, MEAN);
    logits_kernel<<<1, 128, 0, stream>>>(MEAN, fc_w, fc_b, out);
}